// Round 1
// baseline (203.314 us; speedup 1.0000x reference)
//
#include <hip/hip_runtime.h>
#include <cstddef>

#define N_NODES 4096
#define HIDDEN  256
#define NHEAD   4
#define DHEAD   64
#define EDGE_DIM 16
#define DEG     32
#define NEDGE   (N_NODES * DEG)
#define LN_EPS  1e-5f

// ---------------------------------------------------------------------------
// Tiled fp32 GEMM: C[M,Nc] = A[M,K] @ B[K,Nc] + bias (optional ReLU).
// 64x64 block tile, BK=16, 256 threads, 4x4 micro-tile per thread.
// M,Nc,K all multiples of 64/16 here -> no bounds checks.
// ---------------------------------------------------------------------------
template <bool RELU>
__global__ __launch_bounds__(256) void gemm64(const float* __restrict__ A,
                                              const float* __restrict__ B,
                                              const float* __restrict__ bias,
                                              float* __restrict__ C,
                                              int M, int Nc, int K) {
    constexpr int BK = 16;
    __shared__ float As[BK][68];   // [kk][m], pad 68 floats = 272B (16B-aligned rows)
    __shared__ float Bs[BK][68];   // [kk][n]

    const int tid = threadIdx.x;
    const int tx = tid & 15;       // n dim
    const int ty = tid >> 4;       // m dim
    const int row0 = blockIdx.y * 64;
    const int col0 = blockIdx.x * 64;

    // A-tile load map: thread -> (m = tid>>2, k-quad = (tid&3)*4)  (64x16 tile)
    const int am = tid >> 2;
    const int ak = (tid & 3) * 4;
    // B-tile load map: thread -> (kk = tid>>4, n-quad = (tid&15)*4) (16x64 tile)
    const int bkk = tid >> 4;
    const int bn  = (tid & 15) * 4;

    float acc[4][4] = {};

    for (int k0 = 0; k0 < K; k0 += BK) {
        float4 av = *(const float4*)&A[(size_t)(row0 + am) * K + k0 + ak];
        float4 bv = *(const float4*)&B[(size_t)(k0 + bkk) * Nc + col0 + bn];
        As[ak + 0][am] = av.x;
        As[ak + 1][am] = av.y;
        As[ak + 2][am] = av.z;
        As[ak + 3][am] = av.w;
        *(float4*)&Bs[bkk][bn] = bv;
        __syncthreads();

#pragma unroll
        for (int kk = 0; kk < BK; ++kk) {
            float a[4], bb[4];
            *(float4*)a  = *(const float4*)&As[kk][ty * 4];
            *(float4*)bb = *(const float4*)&Bs[kk][tx * 4];
#pragma unroll
            for (int i = 0; i < 4; ++i)
#pragma unroll
                for (int j = 0; j < 4; ++j)
                    acc[i][j] = fmaf(a[i], bb[j], acc[i][j]);
        }
        __syncthreads();
    }

    float4 bvals = *(const float4*)&bias[col0 + tx * 4];
    const float bs[4] = {bvals.x, bvals.y, bvals.z, bvals.w};
#pragma unroll
    for (int i = 0; i < 4; ++i) {
        const int r = row0 + ty * 4 + i;
        float4 o;
        float t0 = acc[i][0] + bs[0];
        float t1 = acc[i][1] + bs[1];
        float t2 = acc[i][2] + bs[2];
        float t3 = acc[i][3] + bs[3];
        if (RELU) {
            t0 = fmaxf(t0, 0.f); t1 = fmaxf(t1, 0.f);
            t2 = fmaxf(t2, 0.f); t3 = fmaxf(t3, 0.f);
        }
        o.x = t0; o.y = t1; o.z = t2; o.w = t3;
        *(float4*)&C[(size_t)r * Nc + col0 + tx * 4] = o;
    }
}

// ---------------------------------------------------------------------------
// Attention: one block per src node (256 thr = 4 waves, wave h = head h).
// Edges of node n are exactly e = n*DEG + j, j in [0,32) (ring graph grouping).
// Computes edge bias (edge_attr @ We + be), dot(q,k)/8, softmax over 32
// neighbors, then P·V. Output attn_out[n, h*64+d].
// ---------------------------------------------------------------------------
__global__ __launch_bounds__(256) void attn_kernel(const float* __restrict__ q,
                                                   const float* __restrict__ k,
                                                   const float* __restrict__ v,
                                                   const int* __restrict__ edge_dst,
                                                   const float* __restrict__ edge_attr,
                                                   const float* __restrict__ We,
                                                   const float* __restrict__ be,
                                                   float* __restrict__ out) {
    const int n = blockIdx.x;
    const int tid = threadIdx.x;
    const int h = tid >> 6;       // wave index = head
    const int lane = tid & 63;

    __shared__ float sQ[HIDDEN];
    __shared__ int   sDst[DEG];
    __shared__ float sWe[EDGE_DIM * NHEAD];
    __shared__ float sP[NHEAD][DEG];

    if (tid < HIDDEN) sQ[tid] = q[(size_t)n * HIDDEN + tid];
    if (tid < DEG) sDst[tid] = edge_dst[n * DEG + tid];
    if (tid < EDGE_DIM * NHEAD) sWe[tid] = We[tid];
    __syncthreads();

    // --- QK^T: lane = half*32 + j ; each lane does 32 of the 64 dims.
    const int j = lane & 31;
    const int half = lane >> 5;
    const int dstj = sDst[j];

    float dot = 0.f;
    const float* krow = k + (size_t)dstj * HIDDEN + h * DHEAD + half * 32;
    const float* qrow = &sQ[h * DHEAD + half * 32];
#pragma unroll 8
    for (int d = 0; d < 32; ++d) dot = fmaf(qrow[d], krow[d], dot);
    dot += __shfl_xor(dot, 32);     // combine halves -> full 64-dim dot
    dot *= 0.125f;                  // 1/sqrt(64)

    // --- edge bias (computed redundantly in both halves, same value)
    float eb = be[h];
    const float* ea = edge_attr + (size_t)(n * DEG + j) * EDGE_DIM;
#pragma unroll
    for (int c = 0; c < EDGE_DIM; ++c) eb = fmaf(ea[c], sWe[c * NHEAD + h], eb);

    float logit = dot + eb;

    // --- softmax over j (32 lanes per half, both halves identical)
    float mx = logit;
#pragma unroll
    for (int off = 16; off >= 1; off >>= 1) mx = fmaxf(mx, __shfl_xor(mx, off));
    float p = __expf(logit - mx);
    float sum = p;
#pragma unroll
    for (int off = 16; off >= 1; off >>= 1) sum += __shfl_xor(sum, off);
    p /= sum;
    if (half == 0) sP[h][j] = p;
    __syncthreads();

    // --- P·V: lane = d (0..63), loop neighbors
    float acc = 0.f;
    const int d = lane;
#pragma unroll 4
    for (int jj = 0; jj < DEG; ++jj) {
        acc = fmaf(sP[h][jj], v[(size_t)sDst[jj] * HIDDEN + h * DHEAD + d], acc);
    }
    out[(size_t)n * HIDDEN + h * DHEAD + d] = acc;
}

// ---------------------------------------------------------------------------
// LayerNorm(x + t) * g + b ; one block (256 thr) per row, 1 feature/thread.
// ---------------------------------------------------------------------------
__global__ __launch_bounds__(256) void ln_residual(const float* __restrict__ xin,
                                                   const float* __restrict__ t,
                                                   const float* __restrict__ g,
                                                   const float* __restrict__ b,
                                                   float* __restrict__ out) {
    const int n = blockIdx.x;
    const int tid = threadIdx.x;
    const size_t base = (size_t)n * HIDDEN;

    float vv = xin[base + tid] + t[base + tid];

    __shared__ float ws1[4], ws2[4];
    float s = vv;
#pragma unroll
    for (int off = 32; off >= 1; off >>= 1) s += __shfl_xor(s, off);
    if ((tid & 63) == 0) ws1[tid >> 6] = s;
    __syncthreads();
    const float mean = (ws1[0] + ws1[1] + ws1[2] + ws1[3]) * (1.f / HIDDEN);

    const float dv = vv - mean;
    float s2 = dv * dv;
#pragma unroll
    for (int off = 32; off >= 1; off >>= 1) s2 += __shfl_xor(s2, off);
    if ((tid & 63) == 0) ws2[tid >> 6] = s2;
    __syncthreads();
    const float var = (ws2[0] + ws2[1] + ws2[2] + ws2[3]) * (1.f / HIDDEN);

    out[base + tid] = dv * rsqrtf(var + LN_EPS) * g[tid] + b[tid];
}

// ---------------------------------------------------------------------------
extern "C" void kernel_launch(void* const* d_in, const int* in_sizes, int n_in,
                              void* d_out, int out_size, void* d_ws, size_t ws_size,
                              hipStream_t stream) {
    const float* x   = (const float*)d_in[0];
    const int*   ei  = (const int*)d_in[1];     // [2,E] int32; row1 = dst
    const float* ea  = (const float*)d_in[2];
    const float* Wq  = (const float*)d_in[3];
    const float* bq  = (const float*)d_in[4];
    const float* Wk  = (const float*)d_in[5];
    const float* bk  = (const float*)d_in[6];
    const float* Wv  = (const float*)d_in[7];
    const float* bv  = (const float*)d_in[8];
    const float* Wo  = (const float*)d_in[9];
    const float* bo  = (const float*)d_in[10];
    const float* We  = (const float*)d_in[11];
    const float* be  = (const float*)d_in[12];
    const float* g1  = (const float*)d_in[13];
    const float* b1  = (const float*)d_in[14];
    const float* g2  = (const float*)d_in[15];
    const float* b2  = (const float*)d_in[16];
    const float* Wf1 = (const float*)d_in[17];
    const float* bf1 = (const float*)d_in[18];
    const float* Wf2 = (const float*)d_in[19];
    const float* bf2 = (const float*)d_in[20];

    // Workspace layout (floats). Peak usage = 6 * N*HID * 4B = 24 MB.
    const size_t NH = (size_t)N_NODES * HIDDEN;
    float* ws    = (float*)d_ws;
    float* q     = ws + 0 * NH;
    float* k     = ws + 1 * NH;
    float* v     = ws + 2 * NH;
    float* attn  = ws + 3 * NH;
    float* oproj = ws + 4 * NH;
    float* y     = ws + 5 * NH;
    float* h1    = ws + 0 * NH;   // reuses q..attn (4*NH) after attention
    float* h2    = ws + 4 * NH;   // reuses oproj after LN1

    const dim3 blk(256);
    const dim3 g256(HIDDEN / 64, N_NODES / 64);      // N=256 outputs
    const dim3 g1024(1024 / 64, N_NODES / 64);       // FFN1 outputs

    gemm64<false><<<g256, blk, 0, stream>>>(x, Wq, bq, q, N_NODES, HIDDEN, HIDDEN);
    gemm64<false><<<g256, blk, 0, stream>>>(x, Wk, bk, k, N_NODES, HIDDEN, HIDDEN);
    gemm64<false><<<g256, blk, 0, stream>>>(x, Wv, bv, v, N_NODES, HIDDEN, HIDDEN);

    attn_kernel<<<N_NODES, blk, 0, stream>>>(q, k, v, ei + NEDGE, ea, We, be, attn);

    gemm64<false><<<g256, blk, 0, stream>>>(attn, Wo, bo, oproj, N_NODES, HIDDEN, HIDDEN);
    ln_residual<<<N_NODES, blk, 0, stream>>>(x, oproj, g1, b1, y);

    gemm64<true ><<<g1024, blk, 0, stream>>>(y, Wf1, bf1, h1, N_NODES, 4 * HIDDEN, HIDDEN);
    gemm64<false><<<g256, blk, 0, stream>>>(h1, Wf2, bf2, h2, N_NODES, HIDDEN, 4 * HIDDEN);
    ln_residual<<<N_NODES, blk, 0, stream>>>(y, h2, g2, b2, (float*)d_out);
}

// Round 3
// 90.231 us; speedup vs baseline: 2.2533x; 2.2533x over previous
//
#include <hip/hip_runtime.h>
#include <cstddef>

#define N_NODES 4096
#define HIDDEN  256
#define NHEAD   4
#define DHEAD   64
#define EDGE_DIM 16
#define DEG     32
#define NEDGE   (N_NODES * DEG)
#define LN_EPS  1e-5f
#define QKV_STRIDE 768

typedef short  s16x8 __attribute__((ext_vector_type(8)));
typedef float  f32x4 __attribute__((ext_vector_type(4)));
typedef unsigned short u16x8 __attribute__((ext_vector_type(8)));
typedef unsigned short u16x4 __attribute__((ext_vector_type(4)));

__device__ __forceinline__ unsigned short f2b(float f) {
    union { float f; unsigned u; } c{f};
    unsigned u = c.u;
    return (unsigned short)((u + 0x7fffu + ((u >> 16) & 1u)) >> 16);
}

// ---------------------------------------------------------------------------
// pack_kernel: blocks 0..191 transpose+convert weights fp32[K][N] -> bf16[N][K]
// (QKV fused into one [768][256]); blocks 192..255 convert x -> bf16;
// block 256 packs bq|bk|bv into bias768.
// ---------------------------------------------------------------------------
__global__ __launch_bounds__(256) void pack_kernel(
    const float* __restrict__ x,
    const float* __restrict__ Wq, const float* __restrict__ Wk,
    const float* __restrict__ Wv, const float* __restrict__ Wo,
    const float* __restrict__ Wf1, const float* __restrict__ Wf2,
    const float* __restrict__ bq, const float* __restrict__ bk,
    const float* __restrict__ bv,
    unsigned short* __restrict__ xb, unsigned short* __restrict__ Wqkv_t,
    unsigned short* __restrict__ Wo_t, unsigned short* __restrict__ Wf1_t,
    unsigned short* __restrict__ Wf2_t, float* __restrict__ bias768) {
    const int b = blockIdx.x;
    const int tid = threadIdx.x;

    if (b < 192) {
        const float* src;
        unsigned short* dst;
        int K, Nn, tt, rowoff = 0;
        if (b < 48) {
            K = 256; Nn = 256;
            int m = b / 16; tt = b % 16;
            src = (m == 0) ? Wq : ((m == 1) ? Wk : Wv);
            dst = Wqkv_t; rowoff = m * 256;
        } else if (b < 64) {
            K = 256; Nn = 256; tt = b - 48; src = Wo; dst = Wo_t;
        } else if (b < 128) {
            K = 256; Nn = 1024; tt = b - 64; src = Wf1; dst = Wf1_t;
        } else {
            K = 1024; Nn = 256; tt = b - 128; src = Wf2; dst = Wf2_t;
        }
        const int tk = K / 64;
        const int k0 = (tt % tk) * 64, n0 = (tt / tk) * 64;

        __shared__ float tile[64][65];
        const int kk = tid >> 2, nq = (tid & 3) * 16;
#pragma unroll
        for (int i = 0; i < 16; i += 4) {
            float4 vv = *(const float4*)&src[(size_t)(k0 + kk) * Nn + n0 + nq + i];
            tile[kk][nq + i + 0] = vv.x;
            tile[kk][nq + i + 1] = vv.y;
            tile[kk][nq + i + 2] = vv.z;
            tile[kk][nq + i + 3] = vv.w;
        }
        __syncthreads();
        const int nn = tid >> 2, kq = (tid & 3) * 16;
        unsigned short tmp[16];
#pragma unroll
        for (int i = 0; i < 16; ++i) tmp[i] = f2b(tile[kq + i][nn]);
        unsigned short* drow = dst + (size_t)(rowoff + n0 + nn) * K + k0 + kq;
        *(u16x8*)(drow + 0) = *(u16x8*)&tmp[0];
        *(u16x8*)(drow + 8) = *(u16x8*)&tmp[8];
    } else if (b < 256) {
        const int b2 = b - 192;
        const float4* xs = (const float4*)x + (size_t)b2 * 4096;
        u16x4* xd = (u16x4*)xb + (size_t)b2 * 4096;
        for (int i = tid; i < 4096; i += 256) {
            float4 vv = xs[i];
            u16x4 o = {f2b(vv.x), f2b(vv.y), f2b(vv.z), f2b(vv.w)};
            xd[i] = o;
        }
    } else {
        bias768[tid]       = bq[tid];
        bias768[256 + tid] = bk[tid];
        bias768[512 + tid] = bv[tid];
    }
}

// ---------------------------------------------------------------------------
// bf16 MFMA GEMM: C[M,N] = A[M,K](bf16) @ Bt[N,K]^T(bf16) + bias(f32).
// 64x64 tile, BK=64, 256 thr = 4 waves (2x2), 16x16x32 MFMA, acc 2x2 frags.
// REGISTER-staged LDS (linear global load -> swizzled ds_write_b128):
// no async global_load_lds, so __syncthreads fully orders all staging.
// Swizzle: LDS[ (r*128) | (c ^ ((r&7)<<4)) ] = global(r, c); read uses the
// same XOR -> bank-conflict-free ds_read_b128 (G4 / T2).
// ---------------------------------------------------------------------------
template <bool RELU, bool OUTB>
__global__ __launch_bounds__(256) void gemm_mfma(const unsigned short* __restrict__ A,
                                                 const unsigned short* __restrict__ Bt,
                                                 const float* __restrict__ bias,
                                                 void* __restrict__ Cout,
                                                 int M, int Nn, int K) {
    __shared__ unsigned short sA[64 * 64];
    __shared__ unsigned short sB[64 * 64];
    const int tid = threadIdx.x;
    const int wave = tid >> 6, lane = tid & 63;
    const int row0 = blockIdx.y * 64, col0 = blockIdx.x * 64;
    const int wr = wave >> 1, wc = wave & 1;

    f32x4 acc[2][2] = {};

    // linear LDS byte offsets this thread stages (2 x 16B for A, same for B)
    const int lo0 = tid * 16;            // 0..4095   (rows 0..31)
    const int lo1 = lo0 + 4096;          // 4096..8191 (rows 32..63)
    const int r0 = lo0 >> 7, c0 = lo0 & 127;
    const int r1 = lo1 >> 7, c1 = lo1 & 127;
    const int so0 = (lo0 & ~127) | (c0 ^ ((r0 & 7) << 4));  // swizzled LDS off
    const int so1 = (lo1 & ~127) | (c1 ^ ((r1 & 7) << 4));

    for (int kt = 0; kt < K; kt += 64) {
        // ---- stage: linear global 16B loads -> swizzled LDS writes ----
        const char* Ab = (const char*)A + ((size_t)row0 * K + kt) * 2;
        const char* Bb = (const char*)Bt + ((size_t)col0 * K + kt) * 2;
        s16x8 a0 = *(const s16x8*)(Ab + (size_t)r0 * (K * 2) + c0);
        s16x8 a1 = *(const s16x8*)(Ab + (size_t)r1 * (K * 2) + c1);
        s16x8 b0 = *(const s16x8*)(Bb + (size_t)r0 * (K * 2) + c0);
        s16x8 b1 = *(const s16x8*)(Bb + (size_t)r1 * (K * 2) + c1);
        *(s16x8*)((char*)sA + so0) = a0;
        *(s16x8*)((char*)sA + so1) = a1;
        *(s16x8*)((char*)sB + so0) = b0;
        *(s16x8*)((char*)sB + so1) = b1;
        __syncthreads();

        const char* sAc = (const char*)sA;
        const char* sBc = (const char*)sB;
#pragma unroll
        for (int kk = 0; kk < 64; kk += 32) {
            const int koffb = (kk + ((lane >> 4) << 3)) * 2;
            s16x8 a[2], bfr[2];
#pragma unroll
            for (int m = 0; m < 2; ++m) {
                const int r = wr * 32 + m * 16 + (lane & 15);
                int off = r * 128 + koffb;
                off ^= (r & 7) << 4;
                a[m] = *(const s16x8*)(sAc + off);
            }
#pragma unroll
            for (int n = 0; n < 2; ++n) {
                const int c = wc * 32 + n * 16 + (lane & 15);
                int off = c * 128 + koffb;
                off ^= (c & 7) << 4;
                bfr[n] = *(const s16x8*)(sBc + off);
            }
#pragma unroll
            for (int m = 0; m < 2; ++m)
#pragma unroll
                for (int n = 0; n < 2; ++n)
                    acc[m][n] = __builtin_amdgcn_mfma_f32_16x16x32_bf16(
                        a[m], bfr[n], acc[m][n], 0, 0, 0);
        }
        __syncthreads();
    }

    // epilogue: C/D layout col=lane&15, row=(lane>>4)*4+j   [m89]
    const int crow = row0 + wr * 32 + ((lane >> 4) << 2);
    const int ccol = col0 + wc * 32 + (lane & 15);
#pragma unroll
    for (int n = 0; n < 2; ++n) {
        const int c = ccol + n * 16;
        const float bv = bias[c];
#pragma unroll
        for (int m = 0; m < 2; ++m) {
#pragma unroll
            for (int j = 0; j < 4; ++j) {
                const int r = crow + m * 16 + j;
                float v = acc[m][n][j] + bv;
                if (RELU) v = fmaxf(v, 0.f);
                if (OUTB)
                    ((unsigned short*)Cout)[(size_t)r * Nn + c] = f2b(v);
                else
                    ((float*)Cout)[(size_t)r * Nn + c] = v;
            }
        }
    }
}

// ---------------------------------------------------------------------------
// Attention on fused qkv fp32 [N][768] (q|k|v). One block per src node,
// wave h = head h. Output bf16 [N][256].
// ---------------------------------------------------------------------------
__global__ __launch_bounds__(256) void attn_kernel(const float* __restrict__ qkv,
                                                   const int* __restrict__ edge_dst,
                                                   const float* __restrict__ edge_attr,
                                                   const float* __restrict__ We,
                                                   const float* __restrict__ be,
                                                   unsigned short* __restrict__ out) {
    const int n = blockIdx.x;
    const int tid = threadIdx.x;
    const int h = tid >> 6;
    const int lane = tid & 63;

    __shared__ float sQ[HIDDEN];
    __shared__ int   sDst[DEG];
    __shared__ float sWe[EDGE_DIM * NHEAD];
    __shared__ float sP[NHEAD][DEG];

    if (tid < HIDDEN) sQ[tid] = qkv[(size_t)n * QKV_STRIDE + tid];
    if (tid < DEG) sDst[tid] = edge_dst[n * DEG + tid];
    if (tid < EDGE_DIM * NHEAD) sWe[tid] = We[tid];
    __syncthreads();

    const int j = lane & 31;
    const int half = lane >> 5;
    const int dstj = sDst[j];

    float dot = 0.f;
    const float* krow = qkv + (size_t)dstj * QKV_STRIDE + 256 + h * DHEAD + half * 32;
    const float* qrow = &sQ[h * DHEAD + half * 32];
#pragma unroll 8
    for (int d = 0; d < 32; ++d) dot = fmaf(qrow[d], krow[d], dot);
    dot += __shfl_xor(dot, 32);
    dot *= 0.125f;

    float eb = be[h];
    const float* ea = edge_attr + (size_t)(n * DEG + j) * EDGE_DIM;
#pragma unroll
    for (int c = 0; c < EDGE_DIM; ++c) eb = fmaf(ea[c], sWe[c * NHEAD + h], eb);

    float logit = dot + eb;

    float mx = logit;
#pragma unroll
    for (int off = 16; off >= 1; off >>= 1) mx = fmaxf(mx, __shfl_xor(mx, off));
    float p = __expf(logit - mx);
    float sum = p;
#pragma unroll
    for (int off = 16; off >= 1; off >>= 1) sum += __shfl_xor(sum, off);
    p /= sum;
    if (half == 0) sP[h][j] = p;
    __syncthreads();

    float acc = 0.f;
    const int d = lane;
#pragma unroll 4
    for (int jj = 0; jj < DEG; ++jj) {
        acc = fmaf(sP[h][jj], qkv[(size_t)sDst[jj] * QKV_STRIDE + 512 + h * DHEAD + d], acc);
    }
    out[(size_t)n * HIDDEN + h * DHEAD + d] = f2b(acc);
}

// ---------------------------------------------------------------------------
// LayerNorm(x + t) * g + b ; fp32 out + optional bf16 aux out.
// ---------------------------------------------------------------------------
__global__ __launch_bounds__(256) void ln_residual(const float* __restrict__ xin,
                                                   const float* __restrict__ t,
                                                   const float* __restrict__ g,
                                                   const float* __restrict__ b,
                                                   float* __restrict__ out,
                                                   unsigned short* __restrict__ outb) {
    const int n = blockIdx.x;
    const int tid = threadIdx.x;
    const size_t base = (size_t)n * HIDDEN;

    float vv = xin[base + tid] + t[base + tid];

    __shared__ float ws1[4], ws2[4];
    float s = vv;
#pragma unroll
    for (int off = 32; off >= 1; off >>= 1) s += __shfl_xor(s, off);
    if ((tid & 63) == 0) ws1[tid >> 6] = s;
    __syncthreads();
    const float mean = (ws1[0] + ws1[1] + ws1[2] + ws1[3]) * (1.f / HIDDEN);

    const float dv = vv - mean;
    float s2 = dv * dv;
#pragma unroll
    for (int off = 32; off >= 1; off >>= 1) s2 += __shfl_xor(s2, off);
    if ((tid & 63) == 0) ws2[tid >> 6] = s2;
    __syncthreads();
    const float var = (ws2[0] + ws2[1] + ws2[2] + ws2[3]) * (1.f / HIDDEN);

    const float res = dv * rsqrtf(var + LN_EPS) * g[tid] + b[tid];
    out[base + tid] = res;
    if (outb) outb[base + tid] = f2b(res);
}

// ---------------------------------------------------------------------------
extern "C" void kernel_launch(void* const* d_in, const int* in_sizes, int n_in,
                              void* d_out, int out_size, void* d_ws, size_t ws_size,
                              hipStream_t stream) {
    const float* x   = (const float*)d_in[0];
    const int*   ei  = (const int*)d_in[1];
    const float* ea  = (const float*)d_in[2];
    const float* Wq  = (const float*)d_in[3];
    const float* bq  = (const float*)d_in[4];
    const float* Wk  = (const float*)d_in[5];
    const float* bk  = (const float*)d_in[6];
    const float* Wv  = (const float*)d_in[7];
    const float* bv  = (const float*)d_in[8];
    const float* Wo  = (const float*)d_in[9];
    const float* bo  = (const float*)d_in[10];
    const float* We  = (const float*)d_in[11];
    const float* be  = (const float*)d_in[12];
    const float* g1  = (const float*)d_in[13];
    const float* b1  = (const float*)d_in[14];
    const float* g2  = (const float*)d_in[15];
    const float* b2  = (const float*)d_in[16];
    const float* Wf1 = (const float*)d_in[17];
    const float* bf1 = (const float*)d_in[18];
    const float* Wf2 = (const float*)d_in[19];
    const float* bf2 = (const float*)d_in[20];

    // ---- workspace layout (byte offsets; peak 22 MB, all write-before-read
    //      within every call; ws_size >= 24MB per round-1 usage) ----
    char* W = (char*)d_ws;
    unsigned short* xb      = (unsigned short*)(W + 0);                    // 2MB  (dead after QKV gemm)
    float*          h2      = (float*)(W + 0);                             // 4MB  (reuses xb+weights region after FFN2)
    unsigned short* Wqkv_t  = (unsigned short*)(W + (2u << 20));           // 384KB [768][256]
    unsigned short* Wo_t    = (unsigned short*)(W + (2u << 20) + 384 * 1024);   // 128KB
    unsigned short* Wf1_t   = (unsigned short*)(W + (2u << 20) + 512 * 1024);   // 512KB [1024][256]
    unsigned short* Wf2_t   = (unsigned short*)(W + (2u << 20) + 1024 * 1024);  // 512KB [256][1024]
    float*          bias768 = (float*)(W + (2u << 20) + 1536 * 1024);      // 3KB
    float*          qkv     = (float*)(W + (4u << 20));                    // 12MB [4096][768] (dead after attn)
    float*          oproj   = (float*)(W + (4u << 20));                    // 4MB  (reuses qkv)
    float*          y       = (float*)(W + (8u << 20));                    // 4MB
    unsigned short* yb      = (unsigned short*)(W + (12u << 20));          // 2MB
    unsigned short* h1b     = (unsigned short*)(W + (14u << 20));          // 8MB [4096][1024]
    unsigned short* attnb   = (unsigned short*)(W + (16u << 20));          // 2MB (dead before h1b write)

    const dim3 blk(256);

    pack_kernel<<<257, blk, 0, stream>>>(x, Wq, Wk, Wv, Wo, Wf1, Wf2, bq, bk, bv,
                                         xb, Wqkv_t, Wo_t, Wf1_t, Wf2_t, bias768);

    gemm_mfma<false, false><<<dim3(12, 64), blk, 0, stream>>>(
        xb, Wqkv_t, bias768, qkv, N_NODES, 768, HIDDEN);

    attn_kernel<<<N_NODES, blk, 0, stream>>>(qkv, ei + NEDGE, ea, We, be, attnb);

    gemm_mfma<false, false><<<dim3(4, 64), blk, 0, stream>>>(
        attnb, Wo_t, bo, oproj, N_NODES, HIDDEN, HIDDEN);

    ln_residual<<<N_NODES, blk, 0, stream>>>(x, oproj, g1, b1, y, yb);

    gemm_mfma<true, true><<<dim3(16, 64), blk, 0, stream>>>(
        yb, Wf1_t, bf1, h1b, N_NODES, 4 * HIDDEN, HIDDEN);

    gemm_mfma<false, false><<<dim3(4, 64), blk, 0, stream>>>(
        h1b, Wf2_t, bf2, h2, N_NODES, HIDDEN, 4 * HIDDEN);

    ln_residual<<<N_NODES, blk, 0, stream>>>(y, h2, g2, b2, (float*)d_out, nullptr);
}

// Round 4
// 77.296 us; speedup vs baseline: 2.6303x; 1.1674x over previous
//
#include <hip/hip_runtime.h>
#include <cstddef>

#define N_NODES 4096
#define HIDDEN  256
#define NHEAD   4
#define DHEAD   64
#define EDGE_DIM 16
#define DEG     32
#define NEDGE   (N_NODES * DEG)
#define LN_EPS  1e-5f
#define QKV_STRIDE 768

typedef short  s16x8 __attribute__((ext_vector_type(8)));
typedef float  f32x4 __attribute__((ext_vector_type(4)));
typedef unsigned short u16x8 __attribute__((ext_vector_type(8)));
typedef unsigned short u16x4 __attribute__((ext_vector_type(4)));

__device__ __forceinline__ unsigned short f2b(float f) {
    union { float f; unsigned u; } c{f};
    unsigned u = c.u;
    return (unsigned short)((u + 0x7fffu + ((u >> 16) & 1u)) >> 16);
}
__device__ __forceinline__ float b2f(unsigned short s) {
    union { unsigned u; float f; } c;
    c.u = ((unsigned)s) << 16;
    return c.f;
}

// ---------------------------------------------------------------------------
// pack_kernel: blocks 0..191 transpose+convert weights fp32[K][N] -> bf16[N][K]
// (QKV fused into one [768][256]); blocks 192..255 convert x -> bf16;
// block 256 packs bq|bk|bv into bias768.
// ---------------------------------------------------------------------------
__global__ __launch_bounds__(256) void pack_kernel(
    const float* __restrict__ x,
    const float* __restrict__ Wq, const float* __restrict__ Wk,
    const float* __restrict__ Wv, const float* __restrict__ Wo,
    const float* __restrict__ Wf1, const float* __restrict__ Wf2,
    const float* __restrict__ bq, const float* __restrict__ bk,
    const float* __restrict__ bv,
    unsigned short* __restrict__ xb, unsigned short* __restrict__ Wqkv_t,
    unsigned short* __restrict__ Wo_t, unsigned short* __restrict__ Wf1_t,
    unsigned short* __restrict__ Wf2_t, float* __restrict__ bias768) {
    const int b = blockIdx.x;
    const int tid = threadIdx.x;

    if (b < 192) {
        const float* src;
        unsigned short* dst;
        int K, Nn, tt, rowoff = 0;
        if (b < 48) {
            K = 256; Nn = 256;
            int m = b / 16; tt = b % 16;
            src = (m == 0) ? Wq : ((m == 1) ? Wk : Wv);
            dst = Wqkv_t; rowoff = m * 256;
        } else if (b < 64) {
            K = 256; Nn = 256; tt = b - 48; src = Wo; dst = Wo_t;
        } else if (b < 128) {
            K = 256; Nn = 1024; tt = b - 64; src = Wf1; dst = Wf1_t;
        } else {
            K = 1024; Nn = 256; tt = b - 128; src = Wf2; dst = Wf2_t;
        }
        const int tk = K / 64;
        const int k0 = (tt % tk) * 64, n0 = (tt / tk) * 64;

        __shared__ float tile[64][65];
        const int kk = tid >> 2, nq = (tid & 3) * 16;
#pragma unroll
        for (int i = 0; i < 16; i += 4) {
            float4 vv = *(const float4*)&src[(size_t)(k0 + kk) * Nn + n0 + nq + i];
            tile[kk][nq + i + 0] = vv.x;
            tile[kk][nq + i + 1] = vv.y;
            tile[kk][nq + i + 2] = vv.z;
            tile[kk][nq + i + 3] = vv.w;
        }
        __syncthreads();
        const int nn = tid >> 2, kq = (tid & 3) * 16;
        unsigned short tmp[16];
#pragma unroll
        for (int i = 0; i < 16; ++i) tmp[i] = f2b(tile[kq + i][nn]);
        unsigned short* drow = dst + (size_t)(rowoff + n0 + nn) * K + k0 + kq;
        *(u16x8*)(drow + 0) = *(u16x8*)&tmp[0];
        *(u16x8*)(drow + 8) = *(u16x8*)&tmp[8];
    } else if (b < 256) {
        const int b2 = b - 192;
        const float4* xs = (const float4*)x + (size_t)b2 * 4096;
        u16x4* xd = (u16x4*)xb + (size_t)b2 * 4096;
        for (int i = tid; i < 4096; i += 256) {
            float4 vv = xs[i];
            u16x4 o = {f2b(vv.x), f2b(vv.y), f2b(vv.z), f2b(vv.w)};
            xd[i] = o;
        }
    } else {
        bias768[tid]       = bq[tid];
        bias768[256 + tid] = bk[tid];
        bias768[512 + tid] = bv[tid];
    }
}

// ---------------------------------------------------------------------------
// bf16 MFMA GEMM (64x64 tile): C = A @ Bt^T + bias. Register-staged LDS with
// XOR swizzle both sides (write+read). Optional ReLU, bf16 or fp32 out.
// ---------------------------------------------------------------------------
template <bool RELU, bool OUTB>
__global__ __launch_bounds__(256) void gemm_mfma(const unsigned short* __restrict__ A,
                                                 const unsigned short* __restrict__ Bt,
                                                 const float* __restrict__ bias,
                                                 void* __restrict__ Cout,
                                                 int M, int Nn, int K) {
    __shared__ unsigned short sA[64 * 64];
    __shared__ unsigned short sB[64 * 64];
    const int tid = threadIdx.x;
    const int wave = tid >> 6, lane = tid & 63;
    const int row0 = blockIdx.y * 64, col0 = blockIdx.x * 64;
    const int wr = wave >> 1, wc = wave & 1;

    f32x4 acc[2][2] = {};

    const int lo0 = tid * 16;
    const int lo1 = lo0 + 4096;
    const int r0 = lo0 >> 7, c0 = lo0 & 127;
    const int r1 = lo1 >> 7, c1 = lo1 & 127;
    const int so0 = (lo0 & ~127) | (c0 ^ ((r0 & 7) << 4));
    const int so1 = (lo1 & ~127) | (c1 ^ ((r1 & 7) << 4));

    for (int kt = 0; kt < K; kt += 64) {
        const char* Ab = (const char*)A + ((size_t)row0 * K + kt) * 2;
        const char* Bb = (const char*)Bt + ((size_t)col0 * K + kt) * 2;
        s16x8 a0 = *(const s16x8*)(Ab + (size_t)r0 * (K * 2) + c0);
        s16x8 a1 = *(const s16x8*)(Ab + (size_t)r1 * (K * 2) + c1);
        s16x8 b0 = *(const s16x8*)(Bb + (size_t)r0 * (K * 2) + c0);
        s16x8 b1 = *(const s16x8*)(Bb + (size_t)r1 * (K * 2) + c1);
        *(s16x8*)((char*)sA + so0) = a0;
        *(s16x8*)((char*)sA + so1) = a1;
        *(s16x8*)((char*)sB + so0) = b0;
        *(s16x8*)((char*)sB + so1) = b1;
        __syncthreads();

        const char* sAc = (const char*)sA;
        const char* sBc = (const char*)sB;
#pragma unroll
        for (int kk = 0; kk < 64; kk += 32) {
            const int koffb = (kk + ((lane >> 4) << 3)) * 2;
            s16x8 a[2], bfr[2];
#pragma unroll
            for (int m = 0; m < 2; ++m) {
                const int r = wr * 32 + m * 16 + (lane & 15);
                int off = r * 128 + koffb;
                off ^= (r & 7) << 4;
                a[m] = *(const s16x8*)(sAc + off);
            }
#pragma unroll
            for (int n = 0; n < 2; ++n) {
                const int c = wc * 32 + n * 16 + (lane & 15);
                int off = c * 128 + koffb;
                off ^= (c & 7) << 4;
                bfr[n] = *(const s16x8*)(sBc + off);
            }
#pragma unroll
            for (int m = 0; m < 2; ++m)
#pragma unroll
                for (int n = 0; n < 2; ++n)
                    acc[m][n] = __builtin_amdgcn_mfma_f32_16x16x32_bf16(
                        a[m], bfr[n], acc[m][n], 0, 0, 0);
        }
        __syncthreads();
    }

    const int crow = row0 + wr * 32 + ((lane >> 4) << 2);
    const int ccol = col0 + wc * 32 + (lane & 15);
#pragma unroll
    for (int n = 0; n < 2; ++n) {
        const int c = ccol + n * 16;
        const float bv = bias[c];
#pragma unroll
        for (int m = 0; m < 2; ++m) {
#pragma unroll
            for (int j = 0; j < 4; ++j) {
                const int r = crow + m * 16 + j;
                float v = acc[m][n][j] + bv;
                if (RELU) v = fmaxf(v, 0.f);
                if (OUTB)
                    ((unsigned short*)Cout)[(size_t)r * Nn + c] = f2b(v);
                else
                    ((float*)Cout)[(size_t)r * Nn + c] = v;
            }
        }
    }
}

// ---------------------------------------------------------------------------
// gemm_ln: fused C = A @ Bt^T + bias ; out = LayerNorm(resid + C)*g + b.
// BM=32 rows x full 256 cols per block (grid = M/32). 4 waves, each wave owns
// 64 cols (wc=wave), acc[2][4]. Per-row mean/var: lane-local sum over n,
// shfl_xor over lane&15 (64 cols/wave), cross-wave via small LDS arrays.
// ---------------------------------------------------------------------------
template <bool WRITE_BF16>
__global__ __launch_bounds__(256) void gemm_ln(const unsigned short* __restrict__ A,
                                               const unsigned short* __restrict__ Bt,
                                               const float* __restrict__ bias,
                                               const float* __restrict__ resid,
                                               const float* __restrict__ g,
                                               const float* __restrict__ b,
                                               float* __restrict__ out,
                                               unsigned short* __restrict__ outb,
                                               int K) {
    __shared__ unsigned short sA[32 * 64];    // 4KB
    __shared__ unsigned short sB[256 * 64];   // 32KB
    __shared__ float rs[32][4], rq[32][4];    // per-row partial sums

    const int tid = threadIdx.x;
    const int wave = tid >> 6, lane = tid & 63;
    const int row0 = blockIdx.x * 32;

    f32x4 acc[2][4] = {};

    // A staging: 4KB -> 1 x 16B per thread
    const int alo = tid * 16;
    const int ar = alo >> 7, ac = alo & 127;
    const int aso = (alo & ~127) | (ac ^ ((ar & 7) << 4));

    for (int kt = 0; kt < K; kt += 64) {
        const char* Ab = (const char*)A + ((size_t)row0 * K + kt) * 2;
        const char* Bb = (const char*)Bt + (size_t)kt * 2;
        s16x8 av = *(const s16x8*)(Ab + (size_t)ar * (K * 2) + ac);
        *(s16x8*)((char*)sA + aso) = av;
        // B staging: 32KB -> 8 x 16B per thread
#pragma unroll
        for (int p = 0; p < 8; ++p) {
            const int lo = tid * 16 + p * 4096;
            const int r = lo >> 7, c = lo & 127;
            const int so = (lo & ~127) | (c ^ ((r & 7) << 4));
            s16x8 bv = *(const s16x8*)(Bb + (size_t)r * (K * 2) + c);
            *(s16x8*)((char*)sB + so) = bv;
        }
        __syncthreads();

        const char* sAc = (const char*)sA;
        const char* sBc = (const char*)sB;
#pragma unroll
        for (int kk = 0; kk < 64; kk += 32) {
            const int koffb = (kk + ((lane >> 4) << 3)) * 2;
            s16x8 a[2], bfr[4];
#pragma unroll
            for (int m = 0; m < 2; ++m) {
                const int r = m * 16 + (lane & 15);
                int off = r * 128 + koffb;
                off ^= (r & 7) << 4;
                a[m] = *(const s16x8*)(sAc + off);
            }
#pragma unroll
            for (int n = 0; n < 4; ++n) {
                const int c = wave * 64 + n * 16 + (lane & 15);
                int off = c * 128 + koffb;
                off ^= (c & 7) << 4;
                bfr[n] = *(const s16x8*)(sBc + off);
            }
#pragma unroll
            for (int m = 0; m < 2; ++m)
#pragma unroll
                for (int n = 0; n < 4; ++n)
                    acc[m][n] = __builtin_amdgcn_mfma_f32_16x16x32_bf16(
                        a[m], bfr[n], acc[m][n], 0, 0, 0);
        }
        __syncthreads();
    }

    // ---- epilogue: val = acc + bias + resid ; per-row LN over 256 cols ----
    const int rbase = ((lane >> 4) << 2);          // local row base (j offset)
    const int cbase = wave * 64 + (lane & 15);

    float sm[2][4], sq[2][4];                      // per (m,j) partials
#pragma unroll
    for (int m = 0; m < 2; ++m) {
#pragma unroll
        for (int j = 0; j < 4; ++j) { sm[m][j] = 0.f; sq[m][j] = 0.f; }
#pragma unroll
        for (int n = 0; n < 4; ++n) {
            const int c = cbase + n * 16;
            const float bv = bias[c];
#pragma unroll
            for (int j = 0; j < 4; ++j) {
                const int r = m * 16 + rbase + j;
                float v = acc[m][n][j] + bv + resid[(size_t)(row0 + r) * HIDDEN + c];
                acc[m][n][j] = v;
                sm[m][j] += v;
                sq[m][j] = fmaf(v, v, sq[m][j]);
            }
        }
        // reduce across the 16 lanes sharing these rows (bits 0..3 of lane)
#pragma unroll
        for (int off = 8; off >= 1; off >>= 1) {
#pragma unroll
            for (int j = 0; j < 4; ++j) {
                sm[m][j] += __shfl_xor(sm[m][j], off);
                sq[m][j] += __shfl_xor(sq[m][j], off);
            }
        }
        if ((lane & 15) == 0) {
#pragma unroll
            for (int j = 0; j < 4; ++j) {
                rs[m * 16 + rbase + j][wave] = sm[m][j];
                rq[m * 16 + rbase + j][wave] = sq[m][j];
            }
        }
    }
    __syncthreads();

#pragma unroll
    for (int m = 0; m < 2; ++m) {
#pragma unroll
        for (int j = 0; j < 4; ++j) {
            const int r = m * 16 + rbase + j;
            const float tot  = rs[r][0] + rs[r][1] + rs[r][2] + rs[r][3];
            const float totq = rq[r][0] + rq[r][1] + rq[r][2] + rq[r][3];
            const float mean = tot * (1.f / HIDDEN);
            const float var  = totq * (1.f / HIDDEN) - mean * mean;
            const float inv  = rsqrtf(var + LN_EPS);
#pragma unroll
            for (int n = 0; n < 4; ++n) {
                const int c = cbase + n * 16;
                const float res = (acc[m][n][j] - mean) * inv * g[c] + b[c];
                out[(size_t)(row0 + r) * HIDDEN + c] = res;
                if (WRITE_BF16)
                    outb[(size_t)(row0 + r) * HIDDEN + c] = f2b(res);
            }
        }
    }
}

// ---------------------------------------------------------------------------
// Attention on fused bf16 qkv [N][768]. One block per src node, wave = head.
// ---------------------------------------------------------------------------
__global__ __launch_bounds__(256) void attn_kernel(const unsigned short* __restrict__ qkv,
                                                   const int* __restrict__ edge_dst,
                                                   const float* __restrict__ edge_attr,
                                                   const float* __restrict__ We,
                                                   const float* __restrict__ be,
                                                   unsigned short* __restrict__ out) {
    const int n = blockIdx.x;
    const int tid = threadIdx.x;
    const int h = tid >> 6;
    const int lane = tid & 63;

    __shared__ float sQ[HIDDEN];
    __shared__ int   sDst[DEG];
    __shared__ float sWe[EDGE_DIM * NHEAD];
    __shared__ float sP[NHEAD][DEG];

    if (tid < HIDDEN) sQ[tid] = b2f(qkv[(size_t)n * QKV_STRIDE + tid]);
    if (tid < DEG) sDst[tid] = edge_dst[n * DEG + tid];
    if (tid < EDGE_DIM * NHEAD) sWe[tid] = We[tid];
    __syncthreads();

    const int j = lane & 31;
    const int half = lane >> 5;
    const int dstj = sDst[j];

    // k-row slice: 32 bf16 = 4 x 16B aligned loads
    float dot = 0.f;
    const unsigned short* krow = qkv + (size_t)dstj * QKV_STRIDE + 256 + h * DHEAD + half * 32;
    const float* qrow = &sQ[h * DHEAD + half * 32];
#pragma unroll
    for (int q8 = 0; q8 < 4; ++q8) {
        u16x8 kv = *(const u16x8*)(krow + q8 * 8);
#pragma unroll
        for (int d = 0; d < 8; ++d)
            dot = fmaf(qrow[q8 * 8 + d], b2f(kv[d]), dot);
    }
    dot += __shfl_xor(dot, 32);
    dot *= 0.125f;

    float eb = be[h];
    const float* ea = edge_attr + (size_t)(n * DEG + j) * EDGE_DIM;
#pragma unroll
    for (int c = 0; c < EDGE_DIM; ++c) eb = fmaf(ea[c], sWe[c * NHEAD + h], eb);

    float logit = dot + eb;

    float mx = logit;
#pragma unroll
    for (int off = 16; off >= 1; off >>= 1) mx = fmaxf(mx, __shfl_xor(mx, off));
    float p = __expf(logit - mx);
    float sum = p;
#pragma unroll
    for (int off = 16; off >= 1; off >>= 1) sum += __shfl_xor(sum, off);
    p /= sum;
    if (half == 0) sP[h][j] = p;
    __syncthreads();

    float acc = 0.f;
    const int d = lane;
#pragma unroll 4
    for (int jj = 0; jj < DEG; ++jj) {
        acc = fmaf(sP[h][jj], b2f(qkv[(size_t)sDst[jj] * QKV_STRIDE + 512 + h * DHEAD + d]), acc);
    }
    out[(size_t)n * HIDDEN + h * DHEAD + d] = f2b(acc);
}

// ---------------------------------------------------------------------------
extern "C" void kernel_launch(void* const* d_in, const int* in_sizes, int n_in,
                              void* d_out, int out_size, void* d_ws, size_t ws_size,
                              hipStream_t stream) {
    const float* x   = (const float*)d_in[0];
    const int*   ei  = (const int*)d_in[1];
    const float* ea  = (const float*)d_in[2];
    const float* Wq  = (const float*)d_in[3];
    const float* bq  = (const float*)d_in[4];
    const float* Wk  = (const float*)d_in[5];
    const float* bk  = (const float*)d_in[6];
    const float* Wv  = (const float*)d_in[7];
    const float* bv  = (const float*)d_in[8];
    const float* Wo  = (const float*)d_in[9];
    const float* bo  = (const float*)d_in[10];
    const float* We  = (const float*)d_in[11];
    const float* be  = (const float*)d_in[12];
    const float* g1  = (const float*)d_in[13];
    const float* b1  = (const float*)d_in[14];
    const float* g2  = (const float*)d_in[15];
    const float* b2  = (const float*)d_in[16];
    const float* Wf1 = (const float*)d_in[17];
    const float* bf1 = (const float*)d_in[18];
    const float* Wf2 = (const float*)d_in[19];
    const float* bf2 = (const float*)d_in[20];

    // ---- workspace layout (all write-before-read within each call) ----
    char* W = (char*)d_ws;
    unsigned short* xb      = (unsigned short*)(W + 0);                         // 2MB
    unsigned short* Wqkv_t  = (unsigned short*)(W + (2u << 20));                // 384KB
    unsigned short* Wo_t    = (unsigned short*)(W + (2u << 20) + 384 * 1024);   // 128KB
    unsigned short* Wf1_t   = (unsigned short*)(W + (2u << 20) + 512 * 1024);   // 512KB
    unsigned short* Wf2_t   = (unsigned short*)(W + (2u << 20) + 1024 * 1024);  // 512KB
    float*          bias768 = (float*)(W + (2u << 20) + 1536 * 1024);           // 3KB
    unsigned short* qkvb    = (unsigned short*)(W + (4u << 20));                // 6MB [4096][768] (dead after attn)
    unsigned short* h1b     = (unsigned short*)(W + (4u << 20));                // 8MB [4096][1024] (reuses qkvb)
    float*          y       = (float*)(W + (12u << 20));                        // 4MB
    unsigned short* yb      = (unsigned short*)(W + (16u << 20));               // 2MB
    unsigned short* attnb   = (unsigned short*)(W + (18u << 20));               // 2MB

    const dim3 blk(256);

    pack_kernel<<<257, blk, 0, stream>>>(x, Wq, Wk, Wv, Wo, Wf1, Wf2, bq, bk, bv,
                                         xb, Wqkv_t, Wo_t, Wf1_t, Wf2_t, bias768);

    // QKV: [4096,256] @ [256,768] -> bf16 qkv
    gemm_mfma<false, true><<<dim3(12, 64), blk, 0, stream>>>(
        xb, Wqkv_t, bias768, qkvb, N_NODES, 768, HIDDEN);

    attn_kernel<<<N_NODES, blk, 0, stream>>>(qkvb, ei + NEDGE, ea, We, be, attnb);

    // O-proj + residual(x) + LN1 -> y (fp32) + yb (bf16)
    gemm_ln<true><<<N_NODES / 32, blk, 0, stream>>>(
        attnb, Wo_t, bo, x, g1, b1, y, yb, HIDDEN);

    // FFN1 + ReLU -> h1b (bf16)
    gemm_mfma<true, true><<<dim3(16, 64), blk, 0, stream>>>(
        yb, Wf1_t, bf1, h1b, N_NODES, 4 * HIDDEN, HIDDEN);

    // FFN2 + residual(y) + LN2 -> d_out (fp32)
    gemm_ln<false><<<N_NODES / 32, blk, 0, stream>>>(
        h1b, Wf2_t, bf2, y, g2, b2, (float*)d_out, nullptr, 4 * HIDDEN);
}

// Round 5
// 75.332 us; speedup vs baseline: 2.6989x; 1.0261x over previous
//
#include <hip/hip_runtime.h>
#include <cstddef>

#define N_NODES 4096
#define HIDDEN  256
#define NHEAD   4
#define DHEAD   64
#define EDGE_DIM 16
#define DEG     32
#define NEDGE   (N_NODES * DEG)
#define LN_EPS  1e-5f
#define QKV_STRIDE 768

typedef short  s16x8 __attribute__((ext_vector_type(8)));
typedef float  f32x4 __attribute__((ext_vector_type(4)));
typedef unsigned short u16x8 __attribute__((ext_vector_type(8)));
typedef unsigned short u16x4 __attribute__((ext_vector_type(4)));

__device__ __forceinline__ unsigned short f2b(float f) {
    union { float f; unsigned u; } c{f};
    unsigned u = c.u;
    return (unsigned short)((u + 0x7fffu + ((u >> 16) & 1u)) >> 16);
}
__device__ __forceinline__ float b2f(unsigned short s) {
    union { unsigned u; float f; } c;
    c.u = ((unsigned)s) << 16;
    return c.f;
}

// ---------------------------------------------------------------------------
// pack_kernel: blocks 0..191 transpose+convert weights fp32[K][N] -> bf16[N][K]
// (QKV fused into one [768][256]); block 192 packs bq|bk|bv into bias768.
// ---------------------------------------------------------------------------
__global__ __launch_bounds__(256) void pack_kernel(
    const float* __restrict__ Wq, const float* __restrict__ Wk,
    const float* __restrict__ Wv, const float* __restrict__ Wo,
    const float* __restrict__ Wf1, const float* __restrict__ Wf2,
    const float* __restrict__ bq, const float* __restrict__ bk,
    const float* __restrict__ bv,
    unsigned short* __restrict__ Wqkv_t, unsigned short* __restrict__ Wo_t,
    unsigned short* __restrict__ Wf1_t, unsigned short* __restrict__ Wf2_t,
    float* __restrict__ bias768) {
    const int b = blockIdx.x;
    const int tid = threadIdx.x;

    if (b < 192) {
        const float* src;
        unsigned short* dst;
        int K, Nn, tt, rowoff = 0;
        if (b < 48) {
            K = 256; Nn = 256;
            int m = b / 16; tt = b % 16;
            src = (m == 0) ? Wq : ((m == 1) ? Wk : Wv);
            dst = Wqkv_t; rowoff = m * 256;
        } else if (b < 64) {
            K = 256; Nn = 256; tt = b - 48; src = Wo; dst = Wo_t;
        } else if (b < 128) {
            K = 256; Nn = 1024; tt = b - 64; src = Wf1; dst = Wf1_t;
        } else {
            K = 1024; Nn = 256; tt = b - 128; src = Wf2; dst = Wf2_t;
        }
        const int tk = K / 64;
        const int k0 = (tt % tk) * 64, n0 = (tt / tk) * 64;

        __shared__ float tile[64][65];
        const int kk = tid >> 2, nq = (tid & 3) * 16;
#pragma unroll
        for (int i = 0; i < 16; i += 4) {
            float4 vv = *(const float4*)&src[(size_t)(k0 + kk) * Nn + n0 + nq + i];
            tile[kk][nq + i + 0] = vv.x;
            tile[kk][nq + i + 1] = vv.y;
            tile[kk][nq + i + 2] = vv.z;
            tile[kk][nq + i + 3] = vv.w;
        }
        __syncthreads();
        const int nn = tid >> 2, kq = (tid & 3) * 16;
        unsigned short tmp[16];
#pragma unroll
        for (int i = 0; i < 16; ++i) tmp[i] = f2b(tile[kq + i][nn]);
        unsigned short* drow = dst + (size_t)(rowoff + n0 + nn) * K + k0 + kq;
        *(u16x8*)(drow + 0) = *(u16x8*)&tmp[0];
        *(u16x8*)(drow + 8) = *(u16x8*)&tmp[8];
    } else {
        bias768[tid]       = bq[tid];
        bias768[256 + tid] = bk[tid];
        bias768[512 + tid] = bv[tid];
    }
}

// ---------------------------------------------------------------------------
// gemm_qkv: qkv[4096,768](bf16) = x(fp32) @ Wqkv_t^T + bias768. 64x64 tile,
// K=256. A staged fp32 -> bf16 in-register during LDS write (removes the xb
// round-trip). XOR swizzle both sides.
// ---------------------------------------------------------------------------
__global__ __launch_bounds__(256) void gemm_qkv(const float* __restrict__ X,
                                                const unsigned short* __restrict__ Bt,
                                                const float* __restrict__ bias,
                                                unsigned short* __restrict__ Cout) {
    __shared__ unsigned short sA[64 * 64];
    __shared__ unsigned short sB[64 * 64];
    const int tid = threadIdx.x;
    const int wave = tid >> 6, lane = tid & 63;
    const int row0 = blockIdx.y * 64, col0 = blockIdx.x * 64;
    const int wr = wave >> 1, wc = wave & 1;

    f32x4 acc[2][2] = {};

    // B staging (bf16, 2 x 16B per thread)
    const int lo0 = tid * 16, lo1 = lo0 + 4096;
    const int r0 = lo0 >> 7, c0 = lo0 & 127;
    const int r1 = lo1 >> 7, c1 = lo1 & 127;
    const int so0 = (lo0 & ~127) | (c0 ^ ((r0 & 7) << 4));
    const int so1 = (lo1 & ~127) | (c1 ^ ((r1 & 7) << 4));

    // A staging (fp32 -> bf16): row ar = tid>>2, 16 k-elems at (tid&3)*16
    const int ar  = tid >> 2;
    const int akb = (tid & 3) * 16;
    const int acb = akb * 2;
    const int axr = (ar & 7) << 4;
    const int aso0 = (ar * 128) | ((acb +  0) ^ axr);
    const int aso1 = (ar * 128) | ((acb + 16) ^ axr);

    for (int kt = 0; kt < 256; kt += 64) {
        const float* Ap = X + (size_t)(row0 + ar) * 256 + kt + akb;
        float4 f0 = *(const float4*)(Ap + 0);
        float4 f1 = *(const float4*)(Ap + 4);
        float4 f2v = *(const float4*)(Ap + 8);
        float4 f3 = *(const float4*)(Ap + 12);
        u16x8 pa0 = {f2b(f0.x), f2b(f0.y), f2b(f0.z), f2b(f0.w),
                     f2b(f1.x), f2b(f1.y), f2b(f1.z), f2b(f1.w)};
        u16x8 pa1 = {f2b(f2v.x), f2b(f2v.y), f2b(f2v.z), f2b(f2v.w),
                     f2b(f3.x), f2b(f3.y), f2b(f3.z), f2b(f3.w)};
        *(u16x8*)((char*)sA + aso0) = pa0;
        *(u16x8*)((char*)sA + aso1) = pa1;

        const char* Bb = (const char*)Bt + ((size_t)col0 * 256 + kt) * 2;
        s16x8 b0 = *(const s16x8*)(Bb + (size_t)r0 * 512 + c0);
        s16x8 b1 = *(const s16x8*)(Bb + (size_t)r1 * 512 + c1);
        *(s16x8*)((char*)sB + so0) = b0;
        *(s16x8*)((char*)sB + so1) = b1;
        __syncthreads();

        const char* sAc = (const char*)sA;
        const char* sBc = (const char*)sB;
#pragma unroll
        for (int kk = 0; kk < 64; kk += 32) {
            const int koffb = (kk + ((lane >> 4) << 3)) * 2;
            s16x8 a[2], bfr[2];
#pragma unroll
            for (int m = 0; m < 2; ++m) {
                const int r = wr * 32 + m * 16 + (lane & 15);
                int off = r * 128 + koffb;
                off ^= (r & 7) << 4;
                a[m] = *(const s16x8*)(sAc + off);
            }
#pragma unroll
            for (int n = 0; n < 2; ++n) {
                const int c = wc * 32 + n * 16 + (lane & 15);
                int off = c * 128 + koffb;
                off ^= (c & 7) << 4;
                bfr[n] = *(const s16x8*)(sBc + off);
            }
#pragma unroll
            for (int m = 0; m < 2; ++m)
#pragma unroll
                for (int n = 0; n < 2; ++n)
                    acc[m][n] = __builtin_amdgcn_mfma_f32_16x16x32_bf16(
                        a[m], bfr[n], acc[m][n], 0, 0, 0);
        }
        __syncthreads();
    }

    const int crow = row0 + wr * 32 + ((lane >> 4) << 2);
    const int ccol = col0 + wc * 32 + (lane & 15);
#pragma unroll
    for (int n = 0; n < 2; ++n) {
        const int c = ccol + n * 16;
        const float bv = bias[c];
#pragma unroll
        for (int m = 0; m < 2; ++m)
#pragma unroll
            for (int j = 0; j < 4; ++j)
                Cout[(size_t)(crow + m * 16 + j) * QKV_STRIDE + c] =
                    f2b(acc[m][n][j] + bv);
    }
}

// ---------------------------------------------------------------------------
// bf16 MFMA GEMM (64x64 tile): C = A @ Bt^T + bias. Register-staged LDS with
// XOR swizzle both sides. Optional ReLU, bf16 or fp32 out.
// ---------------------------------------------------------------------------
template <bool RELU, bool OUTB>
__global__ __launch_bounds__(256) void gemm_mfma(const unsigned short* __restrict__ A,
                                                 const unsigned short* __restrict__ Bt,
                                                 const float* __restrict__ bias,
                                                 void* __restrict__ Cout,
                                                 int M, int Nn, int K) {
    __shared__ unsigned short sA[64 * 64];
    __shared__ unsigned short sB[64 * 64];
    const int tid = threadIdx.x;
    const int wave = tid >> 6, lane = tid & 63;
    const int row0 = blockIdx.y * 64, col0 = blockIdx.x * 64;
    const int wr = wave >> 1, wc = wave & 1;

    f32x4 acc[2][2] = {};

    const int lo0 = tid * 16;
    const int lo1 = lo0 + 4096;
    const int r0 = lo0 >> 7, c0 = lo0 & 127;
    const int r1 = lo1 >> 7, c1 = lo1 & 127;
    const int so0 = (lo0 & ~127) | (c0 ^ ((r0 & 7) << 4));
    const int so1 = (lo1 & ~127) | (c1 ^ ((r1 & 7) << 4));

    for (int kt = 0; kt < K; kt += 64) {
        const char* Ab = (const char*)A + ((size_t)row0 * K + kt) * 2;
        const char* Bb = (const char*)Bt + ((size_t)col0 * K + kt) * 2;
        s16x8 a0 = *(const s16x8*)(Ab + (size_t)r0 * (K * 2) + c0);
        s16x8 a1 = *(const s16x8*)(Ab + (size_t)r1 * (K * 2) + c1);
        s16x8 b0 = *(const s16x8*)(Bb + (size_t)r0 * (K * 2) + c0);
        s16x8 b1 = *(const s16x8*)(Bb + (size_t)r1 * (K * 2) + c1);
        *(s16x8*)((char*)sA + so0) = a0;
        *(s16x8*)((char*)sA + so1) = a1;
        *(s16x8*)((char*)sB + so0) = b0;
        *(s16x8*)((char*)sB + so1) = b1;
        __syncthreads();

        const char* sAc = (const char*)sA;
        const char* sBc = (const char*)sB;
#pragma unroll
        for (int kk = 0; kk < 64; kk += 32) {
            const int koffb = (kk + ((lane >> 4) << 3)) * 2;
            s16x8 a[2], bfr[2];
#pragma unroll
            for (int m = 0; m < 2; ++m) {
                const int r = wr * 32 + m * 16 + (lane & 15);
                int off = r * 128 + koffb;
                off ^= (r & 7) << 4;
                a[m] = *(const s16x8*)(sAc + off);
            }
#pragma unroll
            for (int n = 0; n < 2; ++n) {
                const int c = wc * 32 + n * 16 + (lane & 15);
                int off = c * 128 + koffb;
                off ^= (c & 7) << 4;
                bfr[n] = *(const s16x8*)(sBc + off);
            }
#pragma unroll
            for (int m = 0; m < 2; ++m)
#pragma unroll
                for (int n = 0; n < 2; ++n)
                    acc[m][n] = __builtin_amdgcn_mfma_f32_16x16x32_bf16(
                        a[m], bfr[n], acc[m][n], 0, 0, 0);
        }
        __syncthreads();
    }

    const int crow = row0 + wr * 32 + ((lane >> 4) << 2);
    const int ccol = col0 + wc * 32 + (lane & 15);
#pragma unroll
    for (int n = 0; n < 2; ++n) {
        const int c = ccol + n * 16;
        const float bv = bias[c];
#pragma unroll
        for (int m = 0; m < 2; ++m) {
#pragma unroll
            for (int j = 0; j < 4; ++j) {
                const int r = crow + m * 16 + j;
                float v = acc[m][n][j] + bv;
                if (RELU) v = fmaxf(v, 0.f);
                if (OUTB)
                    ((unsigned short*)Cout)[(size_t)r * Nn + c] = f2b(v);
                else
                    ((float*)Cout)[(size_t)r * Nn + c] = v;
            }
        }
    }
}

// ---------------------------------------------------------------------------
// gemm_ln: fused C = A @ Bt^T + bias ; out = LayerNorm(resid + C)*g + b.
// BM=16 rows x full 256 cols per block (grid = M/16 = 256 -> 1 block/CU).
// 4 waves, wave w owns cols [w*64, w*64+64), acc[4]. Row mean/var via
// shfl_xor over lane bits 0..3 + cross-wave LDS reduce.
// ---------------------------------------------------------------------------
template <bool WRITE_BF16>
__global__ __launch_bounds__(256) void gemm_ln(const unsigned short* __restrict__ A,
                                               const unsigned short* __restrict__ Bt,
                                               const float* __restrict__ bias,
                                               const float* __restrict__ resid,
                                               const float* __restrict__ g,
                                               const float* __restrict__ b,
                                               float* __restrict__ out,
                                               unsigned short* __restrict__ outb,
                                               int K) {
    __shared__ unsigned short sA[16 * 64];    // 2KB
    __shared__ unsigned short sB[256 * 64];   // 32KB
    __shared__ float rs[16][4], rq[16][4];

    const int tid = threadIdx.x;
    const int wave = tid >> 6, lane = tid & 63;
    const int row0 = blockIdx.x * 16;

    f32x4 acc[4] = {};

    const int alo = tid * 16;                 // valid for tid < 128
    const int ar = alo >> 7, ac = alo & 127;
    const int aso = (alo & ~127) | (ac ^ ((ar & 7) << 4));

    for (int kt = 0; kt < K; kt += 64) {
        if (tid < 128) {
            const char* Ab = (const char*)A + ((size_t)row0 * K + kt) * 2;
            s16x8 av = *(const s16x8*)(Ab + (size_t)ar * (K * 2) + ac);
            *(s16x8*)((char*)sA + aso) = av;
        }
        const char* Bb = (const char*)Bt + (size_t)kt * 2;
#pragma unroll
        for (int p = 0; p < 8; ++p) {
            const int lo = tid * 16 + p * 4096;
            const int r = lo >> 7, c = lo & 127;
            const int so = (lo & ~127) | (c ^ ((r & 7) << 4));
            s16x8 bv = *(const s16x8*)(Bb + (size_t)r * (K * 2) + c);
            *(s16x8*)((char*)sB + so) = bv;
        }
        __syncthreads();

        const char* sAc = (const char*)sA;
        const char* sBc = (const char*)sB;
#pragma unroll
        for (int kk = 0; kk < 64; kk += 32) {
            const int koffb = (kk + ((lane >> 4) << 3)) * 2;
            s16x8 a;
            {
                const int r = lane & 15;
                int off = r * 128 + koffb;
                off ^= (r & 7) << 4;
                a = *(const s16x8*)(sAc + off);
            }
            s16x8 bfr[4];
#pragma unroll
            for (int n = 0; n < 4; ++n) {
                const int c = wave * 64 + n * 16 + (lane & 15);
                int off = c * 128 + koffb;
                off ^= (c & 7) << 4;
                bfr[n] = *(const s16x8*)(sBc + off);
            }
#pragma unroll
            for (int n = 0; n < 4; ++n)
                acc[n] = __builtin_amdgcn_mfma_f32_16x16x32_bf16(
                    a, bfr[n], acc[n], 0, 0, 0);
        }
        __syncthreads();
    }

    // ---- epilogue: val = acc + bias + resid ; per-row LN over 256 cols ----
    const int rbase = ((lane >> 4) << 2);
    const int cbase = wave * 64 + (lane & 15);

    float sm[4] = {}, sq_[4] = {};
#pragma unroll
    for (int n = 0; n < 4; ++n) {
        const int c = cbase + n * 16;
        const float bv = bias[c];
#pragma unroll
        for (int j = 0; j < 4; ++j) {
            const int r = rbase + j;
            float v = acc[n][j] + bv + resid[(size_t)(row0 + r) * HIDDEN + c];
            acc[n][j] = v;
            sm[j] += v;
            sq_[j] = fmaf(v, v, sq_[j]);
        }
    }
#pragma unroll
    for (int off = 8; off >= 1; off >>= 1) {
#pragma unroll
        for (int j = 0; j < 4; ++j) {
            sm[j] += __shfl_xor(sm[j], off);
            sq_[j] += __shfl_xor(sq_[j], off);
        }
    }
    if ((lane & 15) == 0) {
#pragma unroll
        for (int j = 0; j < 4; ++j) {
            rs[rbase + j][wave] = sm[j];
            rq[rbase + j][wave] = sq_[j];
        }
    }
    __syncthreads();

#pragma unroll
    for (int j = 0; j < 4; ++j) {
        const int r = rbase + j;
        const float tot  = rs[r][0] + rs[r][1] + rs[r][2] + rs[r][3];
        const float totq = rq[r][0] + rq[r][1] + rq[r][2] + rq[r][3];
        const float mean = tot * (1.f / HIDDEN);
        const float var  = totq * (1.f / HIDDEN) - mean * mean;
        const float inv  = rsqrtf(var + LN_EPS);
#pragma unroll
        for (int n = 0; n < 4; ++n) {
            const int c = cbase + n * 16;
            const float res = (acc[n][j] - mean) * inv * g[c] + b[c];
            out[(size_t)(row0 + r) * HIDDEN + c] = res;
            if (WRITE_BF16)
                outb[(size_t)(row0 + r) * HIDDEN + c] = f2b(res);
        }
    }
}

// ---------------------------------------------------------------------------
// Attention on fused bf16 qkv [N][768]. One block per src node, wave = head.
// ---------------------------------------------------------------------------
__global__ __launch_bounds__(256) void attn_kernel(const unsigned short* __restrict__ qkv,
                                                   const int* __restrict__ edge_dst,
                                                   const float* __restrict__ edge_attr,
                                                   const float* __restrict__ We,
                                                   const float* __restrict__ be,
                                                   unsigned short* __restrict__ out) {
    const int n = blockIdx.x;
    const int tid = threadIdx.x;
    const int h = tid >> 6;
    const int lane = tid & 63;

    __shared__ float sQ[HIDDEN];
    __shared__ int   sDst[DEG];
    __shared__ float sWe[EDGE_DIM * NHEAD];
    __shared__ float sP[NHEAD][DEG];

    if (tid < HIDDEN) sQ[tid] = b2f(qkv[(size_t)n * QKV_STRIDE + tid]);
    if (tid < DEG) sDst[tid] = edge_dst[n * DEG + tid];
    if (tid < EDGE_DIM * NHEAD) sWe[tid] = We[tid];
    __syncthreads();

    const int j = lane & 31;
    const int half = lane >> 5;
    const int dstj = sDst[j];

    float dot = 0.f;
    const unsigned short* krow = qkv + (size_t)dstj * QKV_STRIDE + 256 + h * DHEAD + half * 32;
    const float* qrow = &sQ[h * DHEAD + half * 32];
#pragma unroll
    for (int q8 = 0; q8 < 4; ++q8) {
        u16x8 kv = *(const u16x8*)(krow + q8 * 8);
#pragma unroll
        for (int d = 0; d < 8; ++d)
            dot = fmaf(qrow[q8 * 8 + d], b2f(kv[d]), dot);
    }
    dot += __shfl_xor(dot, 32);
    dot *= 0.125f;

    float eb = be[h];
    const float* ea = edge_attr + (size_t)(n * DEG + j) * EDGE_DIM;
#pragma unroll
    for (int c = 0; c < EDGE_DIM; ++c) eb = fmaf(ea[c], sWe[c * NHEAD + h], eb);

    float logit = dot + eb;

    float mx = logit;
#pragma unroll
    for (int off = 16; off >= 1; off >>= 1) mx = fmaxf(mx, __shfl_xor(mx, off));
    float p = __expf(logit - mx);
    float sum = p;
#pragma unroll
    for (int off = 16; off >= 1; off >>= 1) sum += __shfl_xor(sum, off);
    p /= sum;
    if (half == 0) sP[h][j] = p;
    __syncthreads();

    float acc = 0.f;
    const int d = lane;
#pragma unroll 4
    for (int jj = 0; jj < DEG; ++jj) {
        acc = fmaf(sP[h][jj], b2f(qkv[(size_t)sDst[jj] * QKV_STRIDE + 512 + h * DHEAD + d]), acc);
    }
    out[(size_t)n * HIDDEN + h * DHEAD + d] = f2b(acc);
}

// ---------------------------------------------------------------------------
extern "C" void kernel_launch(void* const* d_in, const int* in_sizes, int n_in,
                              void* d_out, int out_size, void* d_ws, size_t ws_size,
                              hipStream_t stream) {
    const float* x   = (const float*)d_in[0];
    const int*   ei  = (const int*)d_in[1];
    const float* ea  = (const float*)d_in[2];
    const float* Wq  = (const float*)d_in[3];
    const float* bq  = (const float*)d_in[4];
    const float* Wk  = (const float*)d_in[5];
    const float* bk  = (const float*)d_in[6];
    const float* Wv  = (const float*)d_in[7];
    const float* bv  = (const float*)d_in[8];
    const float* Wo  = (const float*)d_in[9];
    const float* bo  = (const float*)d_in[10];
    const float* We  = (const float*)d_in[11];
    const float* be  = (const float*)d_in[12];
    const float* g1  = (const float*)d_in[13];
    const float* b1  = (const float*)d_in[14];
    const float* g2  = (const float*)d_in[15];
    const float* b2  = (const float*)d_in[16];
    const float* Wf1 = (const float*)d_in[17];
    const float* bf1 = (const float*)d_in[18];
    const float* Wf2 = (const float*)d_in[19];
    const float* bf2 = (const float*)d_in[20];

    // ---- workspace layout (all write-before-read within each call) ----
    char* W = (char*)d_ws;
    unsigned short* Wqkv_t  = (unsigned short*)(W + (2u << 20));                // 384KB
    unsigned short* Wo_t    = (unsigned short*)(W + (2u << 20) + 384 * 1024);   // 128KB
    unsigned short* Wf1_t   = (unsigned short*)(W + (2u << 20) + 512 * 1024);   // 512KB
    unsigned short* Wf2_t   = (unsigned short*)(W + (2u << 20) + 1024 * 1024);  // 512KB
    float*          bias768 = (float*)(W + (2u << 20) + 1536 * 1024);           // 3KB
    unsigned short* qkvb    = (unsigned short*)(W + (4u << 20));                // 6MB [4096][768] (dead after attn)
    unsigned short* h1b     = (unsigned short*)(W + (4u << 20));                // 8MB [4096][1024] (reuses qkvb)
    float*          y       = (float*)(W + (12u << 20));                        // 4MB
    unsigned short* yb      = (unsigned short*)(W + (16u << 20));               // 2MB
    unsigned short* attnb   = (unsigned short*)(W + (18u << 20));               // 2MB

    const dim3 blk(256);

    pack_kernel<<<193, blk, 0, stream>>>(Wq, Wk, Wv, Wo, Wf1, Wf2, bq, bk, bv,
                                         Wqkv_t, Wo_t, Wf1_t, Wf2_t, bias768);

    // QKV: x(fp32) @ Wqkv_t -> bf16 qkv (x conversion fused into staging)
    gemm_qkv<<<dim3(12, 64), blk, 0, stream>>>(x, Wqkv_t, bias768, qkvb);

    attn_kernel<<<N_NODES, blk, 0, stream>>>(qkvb, ei + NEDGE, ea, We, be, attnb);

    // O-proj + residual(x) + LN1 -> y (fp32) + yb (bf16)
    gemm_ln<true><<<N_NODES / 16, blk, 0, stream>>>(
        attnb, Wo_t, bo, x, g1, b1, y, yb, HIDDEN);

    // FFN1 + ReLU -> h1b (bf16)
    gemm_mfma<true, true><<<dim3(16, 64), blk, 0, stream>>>(
        yb, Wf1_t, bf1, h1b, N_NODES, 4 * HIDDEN, HIDDEN);

    // FFN2 + residual(y) + LN2 -> d_out (fp32)
    gemm_ln<false><<<N_NODES / 16, blk, 0, stream>>>(
        h1b, Wf2_t, bf2, y, g2, b2, (float*)d_out, nullptr, 4 * HIDDEN);
}

// Round 6
// 69.060 us; speedup vs baseline: 2.9440x; 1.0908x over previous
//
#include <hip/hip_runtime.h>
#include <cstddef>

#define N_NODES 4096
#define HIDDEN  256
#define NHEAD   4
#define DHEAD   64
#define EDGE_DIM 16
#define DEG     32
#define NEDGE   (N_NODES * DEG)
#define LN_EPS  1e-5f
#define QKV_STRIDE 768

typedef short  s16x8 __attribute__((ext_vector_type(8)));
typedef float  f32x4 __attribute__((ext_vector_type(4)));
typedef unsigned short u16x8 __attribute__((ext_vector_type(8)));
typedef unsigned short u16x4 __attribute__((ext_vector_type(4)));

__device__ __forceinline__ unsigned short f2b(float f) {
    union { float f; unsigned u; } c{f};
    unsigned u = c.u;
    return (unsigned short)((u + 0x7fffu + ((u >> 16) & 1u)) >> 16);
}
__device__ __forceinline__ float b2f(unsigned short s) {
    union { unsigned u; float f; } c;
    c.u = ((unsigned)s) << 16;
    return c.f;
}

// ---------------------------------------------------------------------------
// pack_kernel: blocks 0..191 transpose+convert weights fp32[K][N] -> bf16[N][K]
// (QKV fused into one [768][256]); block 192 packs bq|bk|bv into bias768.
// ---------------------------------------------------------------------------
__global__ __launch_bounds__(256) void pack_kernel(
    const float* __restrict__ Wq, const float* __restrict__ Wk,
    const float* __restrict__ Wv, const float* __restrict__ Wo,
    const float* __restrict__ Wf1, const float* __restrict__ Wf2,
    const float* __restrict__ bq, const float* __restrict__ bk,
    const float* __restrict__ bv,
    unsigned short* __restrict__ Wqkv_t, unsigned short* __restrict__ Wo_t,
    unsigned short* __restrict__ Wf1_t, unsigned short* __restrict__ Wf2_t,
    float* __restrict__ bias768) {
    const int b = blockIdx.x;
    const int tid = threadIdx.x;

    if (b < 192) {
        const float* src;
        unsigned short* dst;
        int K, Nn, tt, rowoff = 0;
        if (b < 48) {
            K = 256; Nn = 256;
            int m = b / 16; tt = b % 16;
            src = (m == 0) ? Wq : ((m == 1) ? Wk : Wv);
            dst = Wqkv_t; rowoff = m * 256;
        } else if (b < 64) {
            K = 256; Nn = 256; tt = b - 48; src = Wo; dst = Wo_t;
        } else if (b < 128) {
            K = 256; Nn = 1024; tt = b - 64; src = Wf1; dst = Wf1_t;
        } else {
            K = 1024; Nn = 256; tt = b - 128; src = Wf2; dst = Wf2_t;
        }
        const int tk = K / 64;
        const int k0 = (tt % tk) * 64, n0 = (tt / tk) * 64;

        __shared__ float tile[64][65];
        const int kk = tid >> 2, nq = (tid & 3) * 16;
#pragma unroll
        for (int i = 0; i < 16; i += 4) {
            float4 vv = *(const float4*)&src[(size_t)(k0 + kk) * Nn + n0 + nq + i];
            tile[kk][nq + i + 0] = vv.x;
            tile[kk][nq + i + 1] = vv.y;
            tile[kk][nq + i + 2] = vv.z;
            tile[kk][nq + i + 3] = vv.w;
        }
        __syncthreads();
        const int nn = tid >> 2, kq = (tid & 3) * 16;
        unsigned short tmp[16];
#pragma unroll
        for (int i = 0; i < 16; ++i) tmp[i] = f2b(tile[kq + i][nn]);
        unsigned short* drow = dst + (size_t)(rowoff + n0 + nn) * K + k0 + kq;
        *(u16x8*)(drow + 0) = *(u16x8*)&tmp[0];
        *(u16x8*)(drow + 8) = *(u16x8*)&tmp[8];
    } else {
        bias768[tid]       = bq[tid];
        bias768[256 + tid] = bk[tid];
        bias768[512 + tid] = bv[tid];
    }
}

// ---------------------------------------------------------------------------
// gemm_qkv: qkv[4096,768](bf16) = x(fp32) @ Wqkv_t^T + bias768. 64x64 tile,
// K=256 (4 unrolled k-tiles). Register-rotate prefetch: tile kt+1 is loaded
// into regs between the LDS-ready sync and the MFMAs of tile kt.
// ---------------------------------------------------------------------------
__global__ __launch_bounds__(256) void gemm_qkv(const float* __restrict__ X,
                                                const unsigned short* __restrict__ Bt,
                                                const float* __restrict__ bias,
                                                unsigned short* __restrict__ Cout) {
    __shared__ unsigned short sA[64 * 64];
    __shared__ unsigned short sB[64 * 64];
    const int tid = threadIdx.x;
    const int wave = tid >> 6, lane = tid & 63;
    const int row0 = blockIdx.y * 64, col0 = blockIdx.x * 64;
    const int wr = wave >> 1, wc = wave & 1;

    f32x4 acc[2][2] = {};

    // B staging (bf16, 2 x 16B per thread)
    const int lo0 = tid * 16, lo1 = lo0 + 4096;
    const int r0 = lo0 >> 7, c0 = lo0 & 127;
    const int r1 = lo1 >> 7, c1 = lo1 & 127;
    const int so0 = (lo0 & ~127) | (c0 ^ ((r0 & 7) << 4));
    const int so1 = (lo1 & ~127) | (c1 ^ ((r1 & 7) << 4));

    // A staging (fp32 -> bf16): row ar = tid>>2, 16 k-elems at (tid&3)*16
    const int ar  = tid >> 2;
    const int akb = (tid & 3) * 16;
    const int acb = akb * 2;
    const int axr = (ar & 7) << 4;
    const int aso0 = (ar * 128) | ((acb +  0) ^ axr);
    const int aso1 = (ar * 128) | ((acb + 16) ^ axr);

    float4 f0, f1, f2v, f3;
    s16x8 b0r, b1r;

#define QKV_LOAD(KT)                                                          \
    {                                                                         \
        const float* Ap = X + (size_t)(row0 + ar) * 256 + (KT) * 64 + akb;    \
        f0  = *(const float4*)(Ap + 0);                                       \
        f1  = *(const float4*)(Ap + 4);                                       \
        f2v = *(const float4*)(Ap + 8);                                       \
        f3  = *(const float4*)(Ap + 12);                                      \
        const char* Bb = (const char*)Bt + ((size_t)col0 * 256 + (KT) * 64) * 2; \
        b0r = *(const s16x8*)(Bb + (size_t)r0 * 512 + c0);                    \
        b1r = *(const s16x8*)(Bb + (size_t)r1 * 512 + c1);                    \
    }

    QKV_LOAD(0);
#pragma unroll
    for (int kt = 0; kt < 4; ++kt) {
        if (kt) __syncthreads();      // prior tile's LDS reads complete
        u16x8 pa0 = {f2b(f0.x), f2b(f0.y), f2b(f0.z), f2b(f0.w),
                     f2b(f1.x), f2b(f1.y), f2b(f1.z), f2b(f1.w)};
        u16x8 pa1 = {f2b(f2v.x), f2b(f2v.y), f2b(f2v.z), f2b(f2v.w),
                     f2b(f3.x), f2b(f3.y), f2b(f3.z), f2b(f3.w)};
        *(u16x8*)((char*)sA + aso0) = pa0;
        *(u16x8*)((char*)sA + aso1) = pa1;
        *(s16x8*)((char*)sB + so0) = b0r;
        *(s16x8*)((char*)sB + so1) = b1r;
        __syncthreads();
        if (kt < 3) QKV_LOAD(kt + 1);    // early-issue next tile

        const char* sAc = (const char*)sA;
        const char* sBc = (const char*)sB;
#pragma unroll
        for (int kk = 0; kk < 64; kk += 32) {
            const int koffb = (kk + ((lane >> 4) << 3)) * 2;
            s16x8 a[2], bfr[2];
#pragma unroll
            for (int m = 0; m < 2; ++m) {
                const int r = wr * 32 + m * 16 + (lane & 15);
                int off = r * 128 + koffb;
                off ^= (r & 7) << 4;
                a[m] = *(const s16x8*)(sAc + off);
            }
#pragma unroll
            for (int n = 0; n < 2; ++n) {
                const int c = wc * 32 + n * 16 + (lane & 15);
                int off = c * 128 + koffb;
                off ^= (c & 7) << 4;
                bfr[n] = *(const s16x8*)(sBc + off);
            }
#pragma unroll
            for (int m = 0; m < 2; ++m)
#pragma unroll
                for (int n = 0; n < 2; ++n)
                    acc[m][n] = __builtin_amdgcn_mfma_f32_16x16x32_bf16(
                        a[m], bfr[n], acc[m][n], 0, 0, 0);
        }
    }
#undef QKV_LOAD

    const int crow = row0 + wr * 32 + ((lane >> 4) << 2);
    const int ccol = col0 + wc * 32 + (lane & 15);
#pragma unroll
    for (int n = 0; n < 2; ++n) {
        const int c = ccol + n * 16;
        const float bv = bias[c];
#pragma unroll
        for (int m = 0; m < 2; ++m)
#pragma unroll
            for (int j = 0; j < 4; ++j)
                Cout[(size_t)(crow + m * 16 + j) * QKV_STRIDE + c] =
                    f2b(acc[m][n][j] + bv);
    }
}

// ---------------------------------------------------------------------------
// bf16 MFMA GEMM (64x64 tile, compile-time K): C = A @ Bt^T + bias.
// Register-rotate prefetch, XOR swizzle both sides. ReLU + bf16 out options.
// ---------------------------------------------------------------------------
template <int K, bool RELU, bool OUTB>
__global__ __launch_bounds__(256) void gemm_mfma(const unsigned short* __restrict__ A,
                                                 const unsigned short* __restrict__ Bt,
                                                 const float* __restrict__ bias,
                                                 void* __restrict__ Cout,
                                                 int Nn) {
    constexpr int NT = K / 64;
    __shared__ unsigned short sA[64 * 64];
    __shared__ unsigned short sB[64 * 64];
    const int tid = threadIdx.x;
    const int wave = tid >> 6, lane = tid & 63;
    const int row0 = blockIdx.y * 64, col0 = blockIdx.x * 64;
    const int wr = wave >> 1, wc = wave & 1;

    f32x4 acc[2][2] = {};

    const int lo0 = tid * 16;
    const int lo1 = lo0 + 4096;
    const int r0 = lo0 >> 7, c0 = lo0 & 127;
    const int r1 = lo1 >> 7, c1 = lo1 & 127;
    const int so0 = (lo0 & ~127) | (c0 ^ ((r0 & 7) << 4));
    const int so1 = (lo1 & ~127) | (c1 ^ ((r1 & 7) << 4));

    s16x8 a0r, a1r, b0r, b1r;

#define GM_LOAD(KT)                                                           \
    {                                                                         \
        const char* Ab = (const char*)A + ((size_t)row0 * K + (KT) * 64) * 2; \
        const char* Bb = (const char*)Bt + ((size_t)col0 * K + (KT) * 64) * 2;\
        a0r = *(const s16x8*)(Ab + (size_t)r0 * (K * 2) + c0);                \
        a1r = *(const s16x8*)(Ab + (size_t)r1 * (K * 2) + c1);                \
        b0r = *(const s16x8*)(Bb + (size_t)r0 * (K * 2) + c0);                \
        b1r = *(const s16x8*)(Bb + (size_t)r1 * (K * 2) + c1);                \
    }

    GM_LOAD(0);
#pragma unroll
    for (int kt = 0; kt < NT; ++kt) {
        if (kt) __syncthreads();
        *(s16x8*)((char*)sA + so0) = a0r;
        *(s16x8*)((char*)sA + so1) = a1r;
        *(s16x8*)((char*)sB + so0) = b0r;
        *(s16x8*)((char*)sB + so1) = b1r;
        __syncthreads();
        if (kt + 1 < NT) GM_LOAD(kt + 1);

        const char* sAc = (const char*)sA;
        const char* sBc = (const char*)sB;
#pragma unroll
        for (int kk = 0; kk < 64; kk += 32) {
            const int koffb = (kk + ((lane >> 4) << 3)) * 2;
            s16x8 a[2], bfr[2];
#pragma unroll
            for (int m = 0; m < 2; ++m) {
                const int r = wr * 32 + m * 16 + (lane & 15);
                int off = r * 128 + koffb;
                off ^= (r & 7) << 4;
                a[m] = *(const s16x8*)(sAc + off);
            }
#pragma unroll
            for (int n = 0; n < 2; ++n) {
                const int c = wc * 32 + n * 16 + (lane & 15);
                int off = c * 128 + koffb;
                off ^= (c & 7) << 4;
                bfr[n] = *(const s16x8*)(sBc + off);
            }
#pragma unroll
            for (int m = 0; m < 2; ++m)
#pragma unroll
                for (int n = 0; n < 2; ++n)
                    acc[m][n] = __builtin_amdgcn_mfma_f32_16x16x32_bf16(
                        a[m], bfr[n], acc[m][n], 0, 0, 0);
        }
    }
#undef GM_LOAD

    const int crow = row0 + wr * 32 + ((lane >> 4) << 2);
    const int ccol = col0 + wc * 32 + (lane & 15);
#pragma unroll
    for (int n = 0; n < 2; ++n) {
        const int c = ccol + n * 16;
        const float bv = bias[c];
#pragma unroll
        for (int m = 0; m < 2; ++m) {
#pragma unroll
            for (int j = 0; j < 4; ++j) {
                const int r = crow + m * 16 + j;
                float v = acc[m][n][j] + bv;
                if (RELU) v = fmaxf(v, 0.f);
                if (OUTB)
                    ((unsigned short*)Cout)[(size_t)r * Nn + c] = f2b(v);
                else
                    ((float*)Cout)[(size_t)r * Nn + c] = v;
            }
        }
    }
}

// ---------------------------------------------------------------------------
// gemm_ln: fused C = A @ Bt^T + bias ; out = LayerNorm(resid + C)*g + b.
// BM=16 x 256 cols per block (grid = 256). LDS DOUBLE-BUFFER + register
// prefetch: one __syncthreads per K-step, next tile's global loads issued
// before current tile's MFMAs (T14 issue-early / write-late).
// ---------------------------------------------------------------------------
template <int K, bool WRITE_BF16>
__global__ __launch_bounds__(256) void gemm_ln(const unsigned short* __restrict__ A,
                                               const unsigned short* __restrict__ Bt,
                                               const float* __restrict__ bias,
                                               const float* __restrict__ resid,
                                               const float* __restrict__ g,
                                               const float* __restrict__ b,
                                               float* __restrict__ out,
                                               unsigned short* __restrict__ outb) {
    constexpr int NT = K / 64;
    __shared__ unsigned short sA[2][16 * 64];    // 2 x 2KB
    __shared__ unsigned short sB[2][256 * 64];   // 2 x 32KB
    __shared__ float rs[16][4], rq[16][4];

    const int tid = threadIdx.x;
    const int wave = tid >> 6, lane = tid & 63;
    const int row0 = blockIdx.x * 16;

    f32x4 acc[4] = {};

    const int alo = tid * 16;                 // valid for tid < 128
    const int ar = alo >> 7, ac = alo & 127;
    const int aso = (alo & ~127) | (ac ^ ((ar & 7) << 4));

    s16x8 areg;
    s16x8 breg[8];

#define LN_LOAD(KT)                                                           \
    {                                                                         \
        if (tid < 128) {                                                      \
            const char* Ab = (const char*)A + ((size_t)row0 * K + (KT) * 64) * 2; \
            areg = *(const s16x8*)(Ab + (size_t)ar * (K * 2) + ac);           \
        }                                                                     \
        const char* Bb = (const char*)Bt + ((size_t)(KT) * 64) * 2;           \
        _Pragma("unroll")                                                     \
        for (int p = 0; p < 8; ++p) {                                         \
            const int lo = tid * 16 + p * 4096;                               \
            const int r = lo >> 7, c = lo & 127;                              \
            breg[p] = *(const s16x8*)(Bb + (size_t)r * (K * 2) + c);          \
        }                                                                     \
    }

#define LN_STORE(BUF)                                                         \
    {                                                                         \
        if (tid < 128) *(s16x8*)((char*)sA[BUF] + aso) = areg;                \
        _Pragma("unroll")                                                     \
        for (int p = 0; p < 8; ++p) {                                         \
            const int lo = tid * 16 + p * 4096;                               \
            const int r = lo >> 7, c = lo & 127;                              \
            const int so = (lo & ~127) | (c ^ ((r & 7) << 4));                \
            *(s16x8*)((char*)sB[BUF] + so) = breg[p];                         \
        }                                                                     \
    }

    LN_LOAD(0);
    LN_STORE(0);
    __syncthreads();

#pragma unroll
    for (int kt = 0; kt < NT; ++kt) {
        if (kt + 1 < NT) LN_LOAD(kt + 1);    // early-issue next tile

        const char* sAc = (const char*)sA[kt & 1];
        const char* sBc = (const char*)sB[kt & 1];
#pragma unroll
        for (int kk = 0; kk < 64; kk += 32) {
            const int koffb = (kk + ((lane >> 4) << 3)) * 2;
            s16x8 a;
            {
                const int r = lane & 15;
                int off = r * 128 + koffb;
                off ^= (r & 7) << 4;
                a = *(const s16x8*)(sAc + off);
            }
            s16x8 bfr[4];
#pragma unroll
            for (int n = 0; n < 4; ++n) {
                const int c = wave * 64 + n * 16 + (lane & 15);
                int off = c * 128 + koffb;
                off ^= (c & 7) << 4;
                bfr[n] = *(const s16x8*)(sBc + off);
            }
#pragma unroll
            for (int n = 0; n < 4; ++n)
                acc[n] = __builtin_amdgcn_mfma_f32_16x16x32_bf16(
                    a, bfr[n], acc[n], 0, 0, 0);
        }

        if (kt + 1 < NT) {
            LN_STORE((kt + 1) & 1);          // write-late into the other buffer
            __syncthreads();
        }
    }
#undef LN_LOAD
#undef LN_STORE

    // ---- epilogue: val = acc + bias + resid ; per-row LN over 256 cols ----
    const int rbase = ((lane >> 4) << 2);
    const int cbase = wave * 64 + (lane & 15);

    float sm[4] = {}, sq_[4] = {};
#pragma unroll
    for (int n = 0; n < 4; ++n) {
        const int c = cbase + n * 16;
        const float bv = bias[c];
#pragma unroll
        for (int j = 0; j < 4; ++j) {
            const int r = rbase + j;
            float v = acc[n][j] + bv + resid[(size_t)(row0 + r) * HIDDEN + c];
            acc[n][j] = v;
            sm[j] += v;
            sq_[j] = fmaf(v, v, sq_[j]);
        }
    }
#pragma unroll
    for (int off = 8; off >= 1; off >>= 1) {
#pragma unroll
        for (int j = 0; j < 4; ++j) {
            sm[j] += __shfl_xor(sm[j], off);
            sq_[j] += __shfl_xor(sq_[j], off);
        }
    }
    if ((lane & 15) == 0) {
#pragma unroll
        for (int j = 0; j < 4; ++j) {
            rs[rbase + j][wave] = sm[j];
            rq[rbase + j][wave] = sq_[j];
        }
    }
    __syncthreads();

#pragma unroll
    for (int j = 0; j < 4; ++j) {
        const int r = rbase + j;
        const float tot  = rs[r][0] + rs[r][1] + rs[r][2] + rs[r][3];
        const float totq = rq[r][0] + rq[r][1] + rq[r][2] + rq[r][3];
        const float mean = tot * (1.f / HIDDEN);
        const float var  = totq * (1.f / HIDDEN) - mean * mean;
        const float inv  = rsqrtf(var + LN_EPS);
#pragma unroll
        for (int n = 0; n < 4; ++n) {
            const int c = cbase + n * 16;
            const float res = (acc[n][j] - mean) * inv * g[c] + b[c];
            out[(size_t)(row0 + r) * HIDDEN + c] = res;
            if (WRITE_BF16)
                outb[(size_t)(row0 + r) * HIDDEN + c] = f2b(res);
        }
    }
}

// ---------------------------------------------------------------------------
// Attention on fused bf16 qkv [N][768]. One block per src node, wave = head.
// ---------------------------------------------------------------------------
__global__ __launch_bounds__(256) void attn_kernel(const unsigned short* __restrict__ qkv,
                                                   const int* __restrict__ edge_dst,
                                                   const float* __restrict__ edge_attr,
                                                   const float* __restrict__ We,
                                                   const float* __restrict__ be,
                                                   unsigned short* __restrict__ out) {
    const int n = blockIdx.x;
    const int tid = threadIdx.x;
    const int h = tid >> 6;
    const int lane = tid & 63;

    __shared__ float sQ[HIDDEN];
    __shared__ int   sDst[DEG];
    __shared__ float sWe[EDGE_DIM * NHEAD];
    __shared__ float sP[NHEAD][DEG];

    if (tid < HIDDEN) sQ[tid] = b2f(qkv[(size_t)n * QKV_STRIDE + tid]);
    if (tid < DEG) sDst[tid] = edge_dst[n * DEG + tid];
    if (tid < EDGE_DIM * NHEAD) sWe[tid] = We[tid];
    __syncthreads();

    const int j = lane & 31;
    const int half = lane >> 5;
    const int dstj = sDst[j];

    float dot = 0.f;
    const unsigned short* krow = qkv + (size_t)dstj * QKV_STRIDE + 256 + h * DHEAD + half * 32;
    const float* qrow = &sQ[h * DHEAD + half * 32];
#pragma unroll
    for (int q8 = 0; q8 < 4; ++q8) {
        u16x8 kv = *(const u16x8*)(krow + q8 * 8);
#pragma unroll
        for (int d = 0; d < 8; ++d)
            dot = fmaf(qrow[q8 * 8 + d], b2f(kv[d]), dot);
    }
    dot += __shfl_xor(dot, 32);
    dot *= 0.125f;

    float eb = be[h];
    const float* ea = edge_attr + (size_t)(n * DEG + j) * EDGE_DIM;
#pragma unroll
    for (int c = 0; c < EDGE_DIM; ++c) eb = fmaf(ea[c], sWe[c * NHEAD + h], eb);

    float logit = dot + eb;

    float mx = logit;
#pragma unroll
    for (int off = 16; off >= 1; off >>= 1) mx = fmaxf(mx, __shfl_xor(mx, off));
    float p = __expf(logit - mx);
    float sum = p;
#pragma unroll
    for (int off = 16; off >= 1; off >>= 1) sum += __shfl_xor(sum, off);
    p /= sum;
    if (half == 0) sP[h][j] = p;
    __syncthreads();

    float acc = 0.f;
    const int d = lane;
#pragma unroll 4
    for (int jj = 0; jj < DEG; ++jj) {
        acc = fmaf(sP[h][jj], b2f(qkv[(size_t)sDst[jj] * QKV_STRIDE + 512 + h * DHEAD + d]), acc);
    }
    out[(size_t)n * HIDDEN + h * DHEAD + d] = f2b(acc);
}

// ---------------------------------------------------------------------------
extern "C" void kernel_launch(void* const* d_in, const int* in_sizes, int n_in,
                              void* d_out, int out_size, void* d_ws, size_t ws_size,
                              hipStream_t stream) {
    const float* x   = (const float*)d_in[0];
    const int*   ei  = (const int*)d_in[1];
    const float* ea  = (const float*)d_in[2];
    const float* Wq  = (const float*)d_in[3];
    const float* bq  = (const float*)d_in[4];
    const float* Wk  = (const float*)d_in[5];
    const float* bk  = (const float*)d_in[6];
    const float* Wv  = (const float*)d_in[7];
    const float* bv  = (const float*)d_in[8];
    const float* Wo  = (const float*)d_in[9];
    const float* bo  = (const float*)d_in[10];
    const float* We  = (const float*)d_in[11];
    const float* be  = (const float*)d_in[12];
    const float* g1  = (const float*)d_in[13];
    const float* b1  = (const float*)d_in[14];
    const float* g2  = (const float*)d_in[15];
    const float* b2  = (const float*)d_in[16];
    const float* Wf1 = (const float*)d_in[17];
    const float* bf1 = (const float*)d_in[18];
    const float* Wf2 = (const float*)d_in[19];
    const float* bf2 = (const float*)d_in[20];

    // ---- workspace layout (all write-before-read within each call) ----
    char* W = (char*)d_ws;
    unsigned short* Wqkv_t  = (unsigned short*)(W + (2u << 20));                // 384KB
    unsigned short* Wo_t    = (unsigned short*)(W + (2u << 20) + 384 * 1024);   // 128KB
    unsigned short* Wf1_t   = (unsigned short*)(W + (2u << 20) + 512 * 1024);   // 512KB
    unsigned short* Wf2_t   = (unsigned short*)(W + (2u << 20) + 1024 * 1024);  // 512KB
    float*          bias768 = (float*)(W + (2u << 20) + 1536 * 1024);           // 3KB
    unsigned short* qkvb    = (unsigned short*)(W + (4u << 20));                // 6MB [4096][768] (dead after attn)
    unsigned short* h1b     = (unsigned short*)(W + (4u << 20));                // 8MB [4096][1024] (reuses qkvb)
    float*          y       = (float*)(W + (12u << 20));                        // 4MB
    unsigned short* yb      = (unsigned short*)(W + (16u << 20));               // 2MB
    unsigned short* attnb   = (unsigned short*)(W + (18u << 20));               // 2MB

    const dim3 blk(256);

    pack_kernel<<<193, blk, 0, stream>>>(Wq, Wk, Wv, Wo, Wf1, Wf2, bq, bk, bv,
                                         Wqkv_t, Wo_t, Wf1_t, Wf2_t, bias768);

    // QKV: x(fp32) @ Wqkv_t -> bf16 qkv (x conversion fused into staging)
    gemm_qkv<<<dim3(12, 64), blk, 0, stream>>>(x, Wqkv_t, bias768, qkvb);

    attn_kernel<<<N_NODES, blk, 0, stream>>>(qkvb, ei + NEDGE, ea, We, be, attnb);

    // O-proj + residual(x) + LN1 -> y (fp32) + yb (bf16)
    gemm_ln<256, true><<<N_NODES / 16, blk, 0, stream>>>(
        attnb, Wo_t, bo, x, g1, b1, y, yb);

    // FFN1 + ReLU -> h1b (bf16)
    gemm_mfma<256, true, true><<<dim3(16, 64), blk, 0, stream>>>(
        yb, Wf1_t, bf1, h1b, 4 * HIDDEN);

    // FFN2 + residual(y) + LN2 -> d_out (fp32)
    gemm_ln<1024, false><<<N_NODES / 16, blk, 0, stream>>>(
        h1b, Wf2_t, bf2, y, g2, b2, (float*)d_out, nullptr);
}

// Round 7
// 68.494 us; speedup vs baseline: 2.9683x; 1.0083x over previous
//
#include <hip/hip_runtime.h>
#include <cstddef>

#define N_NODES 4096
#define HIDDEN  256
#define NHEAD   4
#define DHEAD   64
#define EDGE_DIM 16
#define DEG     32
#define NEDGE   (N_NODES * DEG)
#define LN_EPS  1e-5f
#define QKV_STRIDE 768

typedef short  s16x8 __attribute__((ext_vector_type(8)));
typedef float  f32x4 __attribute__((ext_vector_type(4)));
typedef unsigned short u16x8 __attribute__((ext_vector_type(8)));
typedef unsigned short u16x4 __attribute__((ext_vector_type(4)));

__device__ __forceinline__ unsigned short f2b(float f) {
    union { float f; unsigned u; } c{f};
    unsigned u = c.u;
    return (unsigned short)((u + 0x7fffu + ((u >> 16) & 1u)) >> 16);
}
__device__ __forceinline__ float b2f(unsigned short s) {
    union { unsigned u; float f; } c;
    c.u = ((unsigned)s) << 16;
    return c.f;
}

// ---------------------------------------------------------------------------
// pack one 64x64 tile: fp32 src[K][Nn] -> bf16 dst[Nn][K] (transposed), via
// a caller-provided LDS tile (float [64][65]).
// ---------------------------------------------------------------------------
__device__ __forceinline__ void pack_tile(const float* __restrict__ src,
                                          unsigned short* __restrict__ dst,
                                          int K, int Nn, int tt, int rowoff,
                                          float (*tile)[65], int tid) {
    const int tk = K / 64;
    const int k0 = (tt % tk) * 64, n0 = (tt / tk) * 64;

    const int kk = tid >> 2, nq = (tid & 3) * 16;
#pragma unroll
    for (int i = 0; i < 16; i += 4) {
        float4 vv = *(const float4*)&src[(size_t)(k0 + kk) * Nn + n0 + nq + i];
        tile[kk][nq + i + 0] = vv.x;
        tile[kk][nq + i + 1] = vv.y;
        tile[kk][nq + i + 2] = vv.z;
        tile[kk][nq + i + 3] = vv.w;
    }
    __syncthreads();
    const int nn = tid >> 2, kq = (tid & 3) * 16;
    unsigned short tmp[16];
#pragma unroll
    for (int i = 0; i < 16; ++i) tmp[i] = f2b(tile[kq + i][nn]);
    unsigned short* drow = dst + (size_t)(rowoff + n0 + nn) * K + k0 + kq;
    *(u16x8*)(drow + 0) = *(u16x8*)&tmp[0];
    *(u16x8*)(drow + 8) = *(u16x8*)&tmp[8];
}

// ---------------------------------------------------------------------------
// pack_kernel (49 blocks): 0..47 pack Wqkv into [768][256]; 48 packs bias768.
// Wo/Wf1/Wf2 are packed by gemm_qkv's tail blocks (overlapped with QKV GEMM).
// ---------------------------------------------------------------------------
__global__ __launch_bounds__(256) void pack_kernel(
    const float* __restrict__ Wq, const float* __restrict__ Wk,
    const float* __restrict__ Wv,
    const float* __restrict__ bq, const float* __restrict__ bk,
    const float* __restrict__ bv,
    unsigned short* __restrict__ Wqkv_t, float* __restrict__ bias768) {
    const int b = blockIdx.x;
    const int tid = threadIdx.x;
    __shared__ float tile[64][65];

    if (b < 48) {
        int m = b / 16, tt = b % 16;
        const float* src = (m == 0) ? Wq : ((m == 1) ? Wk : Wv);
        pack_tile(src, Wqkv_t, 256, 256, tt, m * 256, tile, tid);
    } else {
        bias768[tid]       = bq[tid];
        bias768[256 + tid] = bk[tid];
        bias768[512 + tid] = bv[tid];
    }
}

// ---------------------------------------------------------------------------
// gemm_qkv (912 blocks): blocks 0..767 compute qkv bf16 = x(fp32) @ Wqkv_t^T
// + bias768 (64x64 tiles, reg-rotate prefetch, XOR swizzle). Blocks 768..911
// pack Wo (16), Wf1 (64), Wf2 (64) — consumed only by later dispatches.
// ---------------------------------------------------------------------------
__global__ __launch_bounds__(256) void gemm_qkv(const float* __restrict__ X,
                                                const unsigned short* __restrict__ Bt,
                                                const float* __restrict__ bias,
                                                unsigned short* __restrict__ Cout,
                                                const float* __restrict__ Wo,
                                                const float* __restrict__ Wf1,
                                                const float* __restrict__ Wf2,
                                                unsigned short* __restrict__ Wo_t,
                                                unsigned short* __restrict__ Wf1_t,
                                                unsigned short* __restrict__ Wf2_t) {
    __shared__ __align__(16) char smem[64 * 65 * 4];   // union: gemm | pack
    const int bid = blockIdx.x;
    const int tid = threadIdx.x;

    if (bid >= 768) {                                   // ---- pack tail ----
        float (*tile)[65] = (float(*)[65])smem;
        const int b2 = bid - 768;
        if (b2 < 16)       pack_tile(Wo,  Wo_t,  256,  256,  b2,      0, tile, tid);
        else if (b2 < 80)  pack_tile(Wf1, Wf1_t, 256,  1024, b2 - 16, 0, tile, tid);
        else               pack_tile(Wf2, Wf2_t, 1024, 256,  b2 - 80, 0, tile, tid);
        return;
    }

    unsigned short* sA = (unsigned short*)smem;         // 8KB
    unsigned short* sB = sA + 64 * 64;                  // 8KB
    const int wave = tid >> 6, lane = tid & 63;
    const int row0 = (bid / 12) * 64, col0 = (bid % 12) * 64;
    const int wr = wave >> 1, wc = wave & 1;

    f32x4 acc[2][2] = {};

    const int lo0 = tid * 16, lo1 = lo0 + 4096;
    const int r0 = lo0 >> 7, c0 = lo0 & 127;
    const int r1 = lo1 >> 7, c1 = lo1 & 127;
    const int so0 = (lo0 & ~127) | (c0 ^ ((r0 & 7) << 4));
    const int so1 = (lo1 & ~127) | (c1 ^ ((r1 & 7) << 4));

    const int ar  = tid >> 2;
    const int akb = (tid & 3) * 16;
    const int acb = akb * 2;
    const int axr = (ar & 7) << 4;
    const int aso0 = (ar * 128) | ((acb +  0) ^ axr);
    const int aso1 = (ar * 128) | ((acb + 16) ^ axr);

    float4 f0, f1, f2v, f3;
    s16x8 b0r, b1r;

#define QKV_LOAD(KT)                                                          \
    {                                                                         \
        const float* Ap = X + (size_t)(row0 + ar) * 256 + (KT) * 64 + akb;    \
        f0  = *(const float4*)(Ap + 0);                                       \
        f1  = *(const float4*)(Ap + 4);                                       \
        f2v = *(const float4*)(Ap + 8);                                       \
        f3  = *(const float4*)(Ap + 12);                                      \
        const char* Bb = (const char*)Bt + ((size_t)col0 * 256 + (KT) * 64) * 2; \
        b0r = *(const s16x8*)(Bb + (size_t)r0 * 512 + c0);                    \
        b1r = *(const s16x8*)(Bb + (size_t)r1 * 512 + c1);                    \
    }

    QKV_LOAD(0);
#pragma unroll
    for (int kt = 0; kt < 4; ++kt) {
        if (kt) __syncthreads();
        u16x8 pa0 = {f2b(f0.x), f2b(f0.y), f2b(f0.z), f2b(f0.w),
                     f2b(f1.x), f2b(f1.y), f2b(f1.z), f2b(f1.w)};
        u16x8 pa1 = {f2b(f2v.x), f2b(f2v.y), f2b(f2v.z), f2b(f2v.w),
                     f2b(f3.x), f2b(f3.y), f2b(f3.z), f2b(f3.w)};
        *(u16x8*)((char*)sA + aso0) = pa0;
        *(u16x8*)((char*)sA + aso1) = pa1;
        *(s16x8*)((char*)sB + so0) = b0r;
        *(s16x8*)((char*)sB + so1) = b1r;
        __syncthreads();
        if (kt < 3) QKV_LOAD(kt + 1);

        const char* sAc = (const char*)sA;
        const char* sBc = (const char*)sB;
#pragma unroll
        for (int kk = 0; kk < 64; kk += 32) {
            const int koffb = (kk + ((lane >> 4) << 3)) * 2;
            s16x8 a[2], bfr[2];
#pragma unroll
            for (int m = 0; m < 2; ++m) {
                const int r = wr * 32 + m * 16 + (lane & 15);
                int off = r * 128 + koffb;
                off ^= (r & 7) << 4;
                a[m] = *(const s16x8*)(sAc + off);
            }
#pragma unroll
            for (int n = 0; n < 2; ++n) {
                const int c = wc * 32 + n * 16 + (lane & 15);
                int off = c * 128 + koffb;
                off ^= (c & 7) << 4;
                bfr[n] = *(const s16x8*)(sBc + off);
            }
#pragma unroll
            for (int m = 0; m < 2; ++m)
#pragma unroll
                for (int n = 0; n < 2; ++n)
                    acc[m][n] = __builtin_amdgcn_mfma_f32_16x16x32_bf16(
                        a[m], bfr[n], acc[m][n], 0, 0, 0);
        }
    }
#undef QKV_LOAD

    const int crow = row0 + wr * 32 + ((lane >> 4) << 2);
    const int ccol = col0 + wc * 32 + (lane & 15);
#pragma unroll
    for (int n = 0; n < 2; ++n) {
        const int c = ccol + n * 16;
        const float bv = bias[c];
#pragma unroll
        for (int m = 0; m < 2; ++m)
#pragma unroll
            for (int j = 0; j < 4; ++j)
                Cout[(size_t)(crow + m * 16 + j) * QKV_STRIDE + c] =
                    f2b(acc[m][n][j] + bv);
    }
}

// ---------------------------------------------------------------------------
// bf16 MFMA GEMM (64x64 tile, compile-time K): C = A @ Bt^T + bias.
// Register-rotate prefetch, XOR swizzle both sides. ReLU + bf16 out options.
// ---------------------------------------------------------------------------
template <int K, bool RELU, bool OUTB>
__global__ __launch_bounds__(256) void gemm_mfma(const unsigned short* __restrict__ A,
                                                 const unsigned short* __restrict__ Bt,
                                                 const float* __restrict__ bias,
                                                 void* __restrict__ Cout,
                                                 int Nn) {
    constexpr int NT = K / 64;
    __shared__ unsigned short sA[64 * 64];
    __shared__ unsigned short sB[64 * 64];
    const int tid = threadIdx.x;
    const int wave = tid >> 6, lane = tid & 63;
    const int row0 = blockIdx.y * 64, col0 = blockIdx.x * 64;
    const int wr = wave >> 1, wc = wave & 1;

    f32x4 acc[2][2] = {};

    const int lo0 = tid * 16;
    const int lo1 = lo0 + 4096;
    const int r0 = lo0 >> 7, c0 = lo0 & 127;
    const int r1 = lo1 >> 7, c1 = lo1 & 127;
    const int so0 = (lo0 & ~127) | (c0 ^ ((r0 & 7) << 4));
    const int so1 = (lo1 & ~127) | (c1 ^ ((r1 & 7) << 4));

    s16x8 a0r, a1r, b0r, b1r;

#define GM_LOAD(KT)                                                           \
    {                                                                         \
        const char* Ab = (const char*)A + ((size_t)row0 * K + (KT) * 64) * 2; \
        const char* Bb = (const char*)Bt + ((size_t)col0 * K + (KT) * 64) * 2;\
        a0r = *(const s16x8*)(Ab + (size_t)r0 * (K * 2) + c0);                \
        a1r = *(const s16x8*)(Ab + (size_t)r1 * (K * 2) + c1);                \
        b0r = *(const s16x8*)(Bb + (size_t)r0 * (K * 2) + c0);                \
        b1r = *(const s16x8*)(Bb + (size_t)r1 * (K * 2) + c1);                \
    }

    GM_LOAD(0);
#pragma unroll
    for (int kt = 0; kt < NT; ++kt) {
        if (kt) __syncthreads();
        *(s16x8*)((char*)sA + so0) = a0r;
        *(s16x8*)((char*)sA + so1) = a1r;
        *(s16x8*)((char*)sB + so0) = b0r;
        *(s16x8*)((char*)sB + so1) = b1r;
        __syncthreads();
        if (kt + 1 < NT) GM_LOAD(kt + 1);

        const char* sAc = (const char*)sA;
        const char* sBc = (const char*)sB;
#pragma unroll
        for (int kk = 0; kk < 64; kk += 32) {
            const int koffb = (kk + ((lane >> 4) << 3)) * 2;
            s16x8 a[2], bfr[2];
#pragma unroll
            for (int m = 0; m < 2; ++m) {
                const int r = wr * 32 + m * 16 + (lane & 15);
                int off = r * 128 + koffb;
                off ^= (r & 7) << 4;
                a[m] = *(const s16x8*)(sAc + off);
            }
#pragma unroll
            for (int n = 0; n < 2; ++n) {
                const int c = wc * 32 + n * 16 + (lane & 15);
                int off = c * 128 + koffb;
                off ^= (c & 7) << 4;
                bfr[n] = *(const s16x8*)(sBc + off);
            }
#pragma unroll
            for (int m = 0; m < 2; ++m)
#pragma unroll
                for (int n = 0; n < 2; ++n)
                    acc[m][n] = __builtin_amdgcn_mfma_f32_16x16x32_bf16(
                        a[m], bfr[n], acc[m][n], 0, 0, 0);
        }
    }
#undef GM_LOAD

    const int crow = row0 + wr * 32 + ((lane >> 4) << 2);
    const int ccol = col0 + wc * 32 + (lane & 15);
#pragma unroll
    for (int n = 0; n < 2; ++n) {
        const int c = ccol + n * 16;
        const float bv = bias[c];
#pragma unroll
        for (int m = 0; m < 2; ++m) {
#pragma unroll
            for (int j = 0; j < 4; ++j) {
                const int r = crow + m * 16 + j;
                float v = acc[m][n][j] + bv;
                if (RELU) v = fmaxf(v, 0.f);
                if (OUTB)
                    ((unsigned short*)Cout)[(size_t)r * Nn + c] = f2b(v);
                else
                    ((float*)Cout)[(size_t)r * Nn + c] = v;
            }
        }
    }
}

// ---------------------------------------------------------------------------
// gemm_ln: fused C = A @ Bt^T + bias ; out = LayerNorm(resid + C)*g + b.
// BM=16 x 256 cols per block (grid = 256), 512 THREADS = 8 waves; wave w owns
// cols [w*32, w*32+32). LDS double-buffer + register prefetch (T14).
// ---------------------------------------------------------------------------
template <int K, bool WRITE_BF16>
__global__ __launch_bounds__(512) void gemm_ln(const unsigned short* __restrict__ A,
                                               const unsigned short* __restrict__ Bt,
                                               const float* __restrict__ bias,
                                               const float* __restrict__ resid,
                                               const float* __restrict__ g,
                                               const float* __restrict__ b,
                                               float* __restrict__ out,
                                               unsigned short* __restrict__ outb) {
    constexpr int NT = K / 64;
    __shared__ unsigned short sA[2][16 * 64];    // 2 x 2KB
    __shared__ unsigned short sB[2][256 * 64];   // 2 x 32KB
    __shared__ float rs[16][8], rq[16][8];

    const int tid = threadIdx.x;
    const int wave = tid >> 6, lane = tid & 63;
    const int row0 = blockIdx.x * 16;

    f32x4 acc[2] = {};

    const int alo = tid * 16;                 // valid for tid < 128
    const int ar = alo >> 7, ac = alo & 127;
    const int aso = (alo & ~127) | (ac ^ ((ar & 7) << 4));

    s16x8 areg;
    s16x8 breg[4];

#define LN_LOAD(KT)                                                           \
    {                                                                         \
        if (tid < 128) {                                                      \
            const char* Ab = (const char*)A + ((size_t)row0 * K + (KT) * 64) * 2; \
            areg = *(const s16x8*)(Ab + (size_t)ar * (K * 2) + ac);           \
        }                                                                     \
        const char* Bb = (const char*)Bt + ((size_t)(KT) * 64) * 2;           \
        _Pragma("unroll")                                                     \
        for (int p = 0; p < 4; ++p) {                                         \
            const int lo = tid * 16 + p * 8192;                               \
            const int r = lo >> 7, c = lo & 127;                              \
            breg[p] = *(const s16x8*)(Bb + (size_t)r * (K * 2) + c);          \
        }                                                                     \
    }

#define LN_STORE(BUF)                                                         \
    {                                                                         \
        if (tid < 128) *(s16x8*)((char*)sA[BUF] + aso) = areg;                \
        _Pragma("unroll")                                                     \
        for (int p = 0; p < 4; ++p) {                                         \
            const int lo = tid * 16 + p * 8192;                               \
            const int r = lo >> 7, c = lo & 127;                              \
            const int so = (lo & ~127) | (c ^ ((r & 7) << 4));                \
            *(s16x8*)((char*)sB[BUF] + so) = breg[p];                         \
        }                                                                     \
    }

    LN_LOAD(0);
    LN_STORE(0);
    __syncthreads();

#pragma unroll
    for (int kt = 0; kt < NT; ++kt) {
        if (kt + 1 < NT) LN_LOAD(kt + 1);    // early-issue next tile

        const char* sAc = (const char*)sA[kt & 1];
        const char* sBc = (const char*)sB[kt & 1];
#pragma unroll
        for (int kk = 0; kk < 64; kk += 32) {
            const int koffb = (kk + ((lane >> 4) << 3)) * 2;
            s16x8 a;
            {
                const int r = lane & 15;
                int off = r * 128 + koffb;
                off ^= (r & 7) << 4;
                a = *(const s16x8*)(sAc + off);
            }
            s16x8 bfr[2];
#pragma unroll
            for (int n = 0; n < 2; ++n) {
                const int c = wave * 32 + n * 16 + (lane & 15);
                int off = c * 128 + koffb;
                off ^= (c & 7) << 4;
                bfr[n] = *(const s16x8*)(sBc + off);
            }
#pragma unroll
            for (int n = 0; n < 2; ++n)
                acc[n] = __builtin_amdgcn_mfma_f32_16x16x32_bf16(
                    a, bfr[n], acc[n], 0, 0, 0);
        }

        if (kt + 1 < NT) {
            LN_STORE((kt + 1) & 1);          // write-late into the other buffer
            __syncthreads();
        }
    }
#undef LN_LOAD
#undef LN_STORE

    // ---- epilogue: val = acc + bias + resid ; per-row LN over 256 cols ----
    const int rbase = ((lane >> 4) << 2);
    const int cbase = wave * 32 + (lane & 15);

    float sm[4] = {}, sq_[4] = {};
#pragma unroll
    for (int n = 0; n < 2; ++n) {
        const int c = cbase + n * 16;
        const float bv = bias[c];
#pragma unroll
        for (int j = 0; j < 4; ++j) {
            const int r = rbase + j;
            float v = acc[n][j] + bv + resid[(size_t)(row0 + r) * HIDDEN + c];
            acc[n][j] = v;
            sm[j] += v;
            sq_[j] = fmaf(v, v, sq_[j]);
        }
    }
#pragma unroll
    for (int off = 8; off >= 1; off >>= 1) {
#pragma unroll
        for (int j = 0; j < 4; ++j) {
            sm[j] += __shfl_xor(sm[j], off);
            sq_[j] += __shfl_xor(sq_[j], off);
        }
    }
    if ((lane & 15) == 0) {
#pragma unroll
        for (int j = 0; j < 4; ++j) {
            rs[rbase + j][wave] = sm[j];
            rq[rbase + j][wave] = sq_[j];
        }
    }
    __syncthreads();

#pragma unroll
    for (int j = 0; j < 4; ++j) {
        const int r = rbase + j;
        float tot = 0.f, totq = 0.f;
#pragma unroll
        for (int w = 0; w < 8; ++w) { tot += rs[r][w]; totq += rq[r][w]; }
        const float mean = tot * (1.f / HIDDEN);
        const float var  = totq * (1.f / HIDDEN) - mean * mean;
        const float inv  = rsqrtf(var + LN_EPS);
#pragma unroll
        for (int n = 0; n < 2; ++n) {
            const int c = cbase + n * 16;
            const float res = (acc[n][j] - mean) * inv * g[c] + b[c];
            out[(size_t)(row0 + r) * HIDDEN + c] = res;
            if (WRITE_BF16)
                outb[(size_t)(row0 + r) * HIDDEN + c] = f2b(res);
        }
    }
}

// ---------------------------------------------------------------------------
// Attention on fused bf16 qkv [N][768]. One block per src node, wave = head.
// ---------------------------------------------------------------------------
__global__ __launch_bounds__(256) void attn_kernel(const unsigned short* __restrict__ qkv,
                                                   const int* __restrict__ edge_dst,
                                                   const float* __restrict__ edge_attr,
                                                   const float* __restrict__ We,
                                                   const float* __restrict__ be,
                                                   unsigned short* __restrict__ out) {
    const int n = blockIdx.x;
    const int tid = threadIdx.x;
    const int h = tid >> 6;
    const int lane = tid & 63;

    __shared__ float sQ[HIDDEN];
    __shared__ int   sDst[DEG];
    __shared__ float sWe[EDGE_DIM * NHEAD];
    __shared__ float sP[NHEAD][DEG];

    if (tid < HIDDEN) sQ[tid] = b2f(qkv[(size_t)n * QKV_STRIDE + tid]);
    if (tid < DEG) sDst[tid] = edge_dst[n * DEG + tid];
    if (tid < EDGE_DIM * NHEAD) sWe[tid] = We[tid];
    __syncthreads();

    const int j = lane & 31;
    const int half = lane >> 5;
    const int dstj = sDst[j];

    float dot = 0.f;
    const unsigned short* krow = qkv + (size_t)dstj * QKV_STRIDE + 256 + h * DHEAD + half * 32;
    const float* qrow = &sQ[h * DHEAD + half * 32];
#pragma unroll
    for (int q8 = 0; q8 < 4; ++q8) {
        u16x8 kv = *(const u16x8*)(krow + q8 * 8);
#pragma unroll
        for (int d = 0; d < 8; ++d)
            dot = fmaf(qrow[q8 * 8 + d], b2f(kv[d]), dot);
    }
    dot += __shfl_xor(dot, 32);
    dot *= 0.125f;

    float eb = be[h];
    const float* ea = edge_attr + (size_t)(n * DEG + j) * EDGE_DIM;
#pragma unroll
    for (int c = 0; c < EDGE_DIM; ++c) eb = fmaf(ea[c], sWe[c * NHEAD + h], eb);

    float logit = dot + eb;

    float mx = logit;
#pragma unroll
    for (int off = 16; off >= 1; off >>= 1) mx = fmaxf(mx, __shfl_xor(mx, off));
    float p = __expf(logit - mx);
    float sum = p;
#pragma unroll
    for (int off = 16; off >= 1; off >>= 1) sum += __shfl_xor(sum, off);
    p /= sum;
    if (half == 0) sP[h][j] = p;
    __syncthreads();

    float acc = 0.f;
    const int d = lane;
#pragma unroll 4
    for (int jj = 0; jj < DEG; ++jj) {
        acc = fmaf(sP[h][jj], b2f(qkv[(size_t)sDst[jj] * QKV_STRIDE + 512 + h * DHEAD + d]), acc);
    }
    out[(size_t)n * HIDDEN + h * DHEAD + d] = f2b(acc);
}

// ---------------------------------------------------------------------------
extern "C" void kernel_launch(void* const* d_in, const int* in_sizes, int n_in,
                              void* d_out, int out_size, void* d_ws, size_t ws_size,
                              hipStream_t stream) {
    const float* x   = (const float*)d_in[0];
    const int*   ei  = (const int*)d_in[1];
    const float* ea  = (const float*)d_in[2];
    const float* Wq  = (const float*)d_in[3];
    const float* bq  = (const float*)d_in[4];
    const float* Wk  = (const float*)d_in[5];
    const float* bk  = (const float*)d_in[6];
    const float* Wv  = (const float*)d_in[7];
    const float* bv  = (const float*)d_in[8];
    const float* Wo  = (const float*)d_in[9];
    const float* bo  = (const float*)d_in[10];
    const float* We  = (const float*)d_in[11];
    const float* be  = (const float*)d_in[12];
    const float* g1  = (const float*)d_in[13];
    const float* b1  = (const float*)d_in[14];
    const float* g2  = (const float*)d_in[15];
    const float* b2  = (const float*)d_in[16];
    const float* Wf1 = (const float*)d_in[17];
    const float* bf1 = (const float*)d_in[18];
    const float* Wf2 = (const float*)d_in[19];
    const float* bf2 = (const float*)d_in[20];

    // ---- workspace layout (all write-before-read within each call) ----
    char* W = (char*)d_ws;
    unsigned short* Wqkv_t  = (unsigned short*)(W + (2u << 20));                // 384KB
    unsigned short* Wo_t    = (unsigned short*)(W + (2u << 20) + 384 * 1024);   // 128KB
    unsigned short* Wf1_t   = (unsigned short*)(W + (2u << 20) + 512 * 1024);   // 512KB
    unsigned short* Wf2_t   = (unsigned short*)(W + (2u << 20) + 1024 * 1024);  // 512KB
    float*          bias768 = (float*)(W + (2u << 20) + 1536 * 1024);           // 3KB
    unsigned short* qkvb    = (unsigned short*)(W + (4u << 20));                // 6MB [4096][768] (dead after attn)
    unsigned short* h1b     = (unsigned short*)(W + (4u << 20));                // 8MB [4096][1024] (reuses qkvb)
    float*          y       = (float*)(W + (12u << 20));                        // 4MB
    unsigned short* yb      = (unsigned short*)(W + (16u << 20));               // 2MB
    unsigned short* attnb   = (unsigned short*)(W + (18u << 20));               // 2MB

    const dim3 blk(256);

    // Wqkv + bias only (49 blocks); Wo/Wf1/Wf2 packed inside gemm_qkv's tail
    pack_kernel<<<49, blk, 0, stream>>>(Wq, Wk, Wv, bq, bk, bv, Wqkv_t, bias768);

    // QKV GEMM (768 tiles) + pack tail (144 blocks)
    gemm_qkv<<<912, blk, 0, stream>>>(x, Wqkv_t, bias768, qkvb,
                                      Wo, Wf1, Wf2, Wo_t, Wf1_t, Wf2_t);

    attn_kernel<<<N_NODES, blk, 0, stream>>>(qkvb, ei + NEDGE, ea, We, be, attnb);

    // O-proj + residual(x) + LN1 -> y (fp32) + yb (bf16)
    gemm_ln<256, true><<<N_NODES / 16, dim3(512), 0, stream>>>(
        attnb, Wo_t, bo, x, g1, b1, y, yb);

    // FFN1 + ReLU -> h1b (bf16)
    gemm_mfma<256, true, true><<<dim3(16, 64), blk, 0, stream>>>(
        yb, Wf1_t, bf1, h1b, 4 * HIDDEN);

    // FFN2 + residual(y) + LN2 -> d_out (fp32)
    gemm_ln<1024, false><<<N_NODES / 16, dim3(512), 0, stream>>>(
        h1b, Wf2_t, bf2, y, g2, b2, (float*)d_out, nullptr);
}